// Round 2
// baseline (1035.638 us; speedup 1.0000x reference)
//
#include <hip/hip_runtime.h>
#include <hip/hip_bf16.h>

typedef unsigned short ushort_t;
typedef short short8 __attribute__((ext_vector_type(8)));
typedef short short4v __attribute__((ext_vector_type(4)));
typedef float floatx4 __attribute__((ext_vector_type(4)));

#define MFMA16(a,b,c) __builtin_amdgcn_mfma_f32_16x16x32_bf16((a),(b),(c),0,0,0)

#define D_MODEL 2048
#define NHEAD   16
#define DK      128
#define SEQ     2048
#define BATCH   2

static __device__ __forceinline__ ushort_t f2bf(float f){
  union { float f; unsigned int i; } v; v.f = f;
  unsigned int r = v.i + 0x7FFFu + ((v.i >> 16) & 1u);
  return (ushort_t)(r >> 16);
}

// ---------------- f32 -> bf16 convert (x -> xb) ----------------
__global__ __launch_bounds__(256) void cvt_k(const float* __restrict__ in,
                                             ushort_t* __restrict__ out) {
  int i = (blockIdx.x * 256 + threadIdx.x) * 8;
  floatx4 a = *(const floatx4*)&in[i];
  floatx4 b = *(const floatx4*)&in[i + 4];
  short8 r;
  for (int j = 0; j < 4; ++j) r[j] = (short)f2bf(a[j]);
  for (int j = 0; j < 4; ++j) r[4 + j] = (short)f2bf(b[j]);
  *(short8*)&out[i] = r;
}

// ---------------- transpose+convert: in f32 [R,C] -> out bf16 [C,R] ----------------
__global__ __launch_bounds__(256) void transpose_cvt_k(const float* __restrict__ in,
                                                       ushort_t* __restrict__ out,
                                                       int R, int C) {
  __shared__ ushort_t tile[64][65];
  int tr = blockIdx.y * 64, tc = blockIdx.x * 64;
  int t = threadIdx.x;
  for (int p = 0; p < 16; ++p) {
    int idx = t + p * 256;
    int r = idx >> 6, c = idx & 63;
    tile[r][c] = f2bf(in[(size_t)(tr + r) * C + (tc + c)]);
  }
  __syncthreads();
  for (int p = 0; p < 16; ++p) {
    int idx = t + p * 256;
    int r = idx >> 6, c = idx & 63;
    out[(size_t)(tc + r) * R + (tr + c)] = tile[c][r];
  }
}

// ---------------- NT GEMM: C = A[M,K](bf16) * BT[N,K](bf16)^T + bias(f32) ----------------
// MODE 0: QKV projection -> scatter to q_ws [B,H,S,DK], k_ws [B,H,S,DK], vT_ws [B,H,DK,S] (bf16)
// MODE 1: output projection -> outp [M,N] f32 row-major
template <int MODE>
__global__ __launch_bounds__(256) void gemm_nt(const ushort_t* __restrict__ A,
                                               const ushort_t* __restrict__ BT,
                                               const float* __restrict__ bias,
                                               ushort_t* __restrict__ out_q,
                                               ushort_t* __restrict__ out_k,
                                               ushort_t* __restrict__ out_v,
                                               float* __restrict__ outp,
                                               int M, int N, int K) {
  __shared__ __align__(16) ushort_t As[128][40];
  __shared__ __align__(16) ushort_t Bs[128][40];
  const int bn = blockIdx.x, bm = blockIdx.y;
  const int t = threadIdx.x;
  const int wave = t >> 6, lane = t & 63;
  const int wr = (wave >> 1) * 64, wc = (wave & 1) * 64;
  const int l15 = lane & 15, lg = lane >> 4;
  const int row0 = bm * 128, col0 = bn * 128;

  floatx4 acc[4][4];
  for (int m = 0; m < 4; ++m) for (int n = 0; n < 4; ++n) acc[m][n] = (floatx4){0.f,0.f,0.f,0.f};

  const int sr = t >> 2;
  const int sc = (t & 3) * 8;

  for (int k0 = 0; k0 < K; k0 += 32) {
    *(short8*)&As[sr][sc]      = *(const short8*)&A[(size_t)(row0 + sr) * K + k0 + sc];
    *(short8*)&As[sr + 64][sc] = *(const short8*)&A[(size_t)(row0 + sr + 64) * K + k0 + sc];
    *(short8*)&Bs[sr][sc]      = *(const short8*)&BT[(size_t)(col0 + sr) * K + k0 + sc];
    *(short8*)&Bs[sr + 64][sc] = *(const short8*)&BT[(size_t)(col0 + sr + 64) * K + k0 + sc];
    __syncthreads();
    short8 af[4], bfr[4];
    for (int m = 0; m < 4; ++m) af[m]  = *(const short8*)&As[wr + m * 16 + l15][lg * 8];
    for (int n = 0; n < 4; ++n) bfr[n] = *(const short8*)&Bs[wc + n * 16 + l15][lg * 8];
    for (int m = 0; m < 4; ++m)
      for (int n = 0; n < 4; ++n)
        acc[m][n] = MFMA16(af[m], bfr[n], acc[m][n]);
    __syncthreads();
  }

  if (MODE == 1) {
    for (int m = 0; m < 4; ++m)
      for (int n = 0; n < 4; ++n) {
        int c = col0 + wc + n * 16 + l15;
        float bv = bias[c];
        int r0 = row0 + wr + m * 16 + lg * 4;
        for (int j = 0; j < 4; ++j)
          outp[(size_t)(r0 + j) * N + c] = acc[m][n][j] + bv;
      }
  } else {
    // column tile bn maps to head h = bn/3, which = bn%3 (q,k,v)
    const int h = bn / 3, which = bn - h * 3;
    for (int m = 0; m < 4; ++m)
      for (int n = 0; n < 4; ++n) {
        int d = wc + n * 16 + l15;
        float bv = bias[col0 + d];
        int r0 = row0 + wr + m * 16 + lg * 4;   // global row = b*SEQ + s
        int b = r0 >> 11;
        int s0 = r0 & 2047;
        if (which < 2) {
          ushort_t* dst = (which == 0) ? out_q : out_k;
          size_t base = ((size_t)(b * NHEAD + h) * SEQ) * DK;
          for (int j = 0; j < 4; ++j)
            dst[base + (size_t)(s0 + j) * DK + d] = f2bf(acc[m][n][j] + bv);
        } else {
          size_t base = ((size_t)(b * NHEAD + h) * DK + d) * SEQ + s0;
          short4v tmp;
          for (int j = 0; j < 4; ++j) tmp[j] = (short)f2bf(acc[m][n][j] + bv);
          *(short4v*)&out_v[base] = tmp;   // contiguous along s
        }
      }
  }
}

// ---------------- flash attention ----------------
// grid: (S/64, B*H). block 256 = 4 waves, each wave owns 16 q-rows.
__global__ __launch_bounds__(256) void attn_k(const ushort_t* __restrict__ qws,
                                              const ushort_t* __restrict__ kws,
                                              const ushort_t* __restrict__ vtws,
                                              ushort_t* __restrict__ ctx) {
  const int bh = blockIdx.y;
  const int qt = blockIdx.x;
  const int b = bh >> 4, h = bh & 15;
  const int t = threadIdx.x, wave = t >> 6, lane = t & 63;
  const int l15 = lane & 15, lg = lane >> 4;

  const ushort_t* Q  = qws  + (size_t)bh * SEQ * DK;
  const ushort_t* Kp = kws  + (size_t)bh * SEQ * DK;
  const ushort_t* VT = vtws + (size_t)bh * DK * SEQ;

  const int qr = qt * 64 + wave * 16;   // wave's q-row base

  short8 qf[4];
  for (int kk = 0; kk < 4; ++kk)
    qf[kk] = *(const short8*)&Q[(size_t)(qr + l15) * DK + kk * 32 + lg * 8];

  floatx4 o[8];
  for (int n = 0; n < 8; ++n) o[n] = (floatx4){0.f,0.f,0.f,0.f};
  float mrow[4], lrow[4];
  for (int j = 0; j < 4; ++j) { mrow[j] = -1e30f; lrow[j] = 0.f; }

  __shared__ __align__(16) ushort_t P[4][16][32];
  const float scale = 0.08838834764831845f;  // 1/sqrt(128)

  for (int kv = 0; kv < SEQ; kv += 32) {
    floatx4 s0 = (floatx4){0.f,0.f,0.f,0.f};
    floatx4 s1 = (floatx4){0.f,0.f,0.f,0.f};
    for (int kk = 0; kk < 4; ++kk) {
      short8 kf0 = *(const short8*)&Kp[(size_t)(kv + l15) * DK + kk * 32 + lg * 8];
      short8 kf1 = *(const short8*)&Kp[(size_t)(kv + 16 + l15) * DK + kk * 32 + lg * 8];
      s0 = MFMA16(qf[kk], kf0, s0);
      s1 = MFMA16(qf[kk], kf1, s1);
    }
    float mloc[4];
    for (int j = 0; j < 4; ++j) {
      s0[j] *= scale; s1[j] *= scale;
      mloc[j] = fmaxf(s0[j], s1[j]);
    }
    for (int off = 1; off < 16; off <<= 1)
      for (int j = 0; j < 4; ++j)
        mloc[j] = fmaxf(mloc[j], __shfl_xor(mloc[j], off, 64));

    float p0[4], p1[4];
    for (int j = 0; j < 4; ++j) {
      float mnew = fmaxf(mrow[j], mloc[j]);
      float corr = __expf(mrow[j] - mnew);
      mrow[j] = mnew;
      p0[j] = __expf(s0[j] - mnew);
      p1[j] = __expf(s1[j] - mnew);
      lrow[j] = lrow[j] * corr + p0[j] + p1[j];
      for (int n = 0; n < 8; ++n) o[n][j] *= corr;
    }
    for (int j = 0; j < 4; ++j) {
      P[wave][lg * 4 + j][l15]      = f2bf(p0[j]);
      P[wave][lg * 4 + j][16 + l15] = f2bf(p1[j]);
    }
    __syncthreads();
    short8 pf = *(const short8*)&P[wave][l15][lg * 8];
    for (int n = 0; n < 8; ++n) {
      short8 vf = *(const short8*)&VT[(size_t)(n * 16 + l15) * SEQ + kv + lg * 8];
      o[n] = MFMA16(pf, vf, o[n]);
    }
    __syncthreads();
  }

  for (int off = 1; off < 16; off <<= 1)
    for (int j = 0; j < 4; ++j)
      lrow[j] += __shfl_xor(lrow[j], off, 64);

  for (int n = 0; n < 8; ++n)
    for (int j = 0; j < 4; ++j) {
      float val = o[n][j] / lrow[j];
      ctx[(size_t)(b * SEQ + qr + lg * 4 + j) * D_MODEL + h * DK + n * 16 + l15] = f2bf(val);
    }
}

// ---------------- launch ----------------
extern "C" void kernel_launch(void* const* d_in, const int* in_sizes, int n_in,
                              void* d_out, int out_size, void* d_ws, size_t ws_size,
                              hipStream_t stream) {
  const float* x    = (const float*)d_in[0];
  const float* Wqkv = (const float*)d_in[1];
  const float* bqkv = (const float*)d_in[2];
  const float* Wout = (const float*)d_in[3];
  const float* bout = (const float*)d_in[4];
  float* out = (float*)d_out;

  ushort_t* WqkvT = (ushort_t*)d_ws;                         // 6144*2048
  ushort_t* WoutT = WqkvT + (size_t)6144 * 2048;             // 2048*2048
  ushort_t* qws   = WoutT + (size_t)2048 * 2048;             // [B,H,S,DK]
  ushort_t* kws   = qws + (size_t)8388608;
  ushort_t* vtws  = kws + (size_t)8388608;                   // [B,H,DK,S]
  ushort_t* ctx   = vtws + (size_t)8388608;                  // [B,S,D]
  ushort_t* xb    = ctx + (size_t)8388608;                   // [B*S, D] bf16

  cvt_k<<<4096, 256, 0, stream>>>(x, xb);
  transpose_cvt_k<<<dim3(6144 / 64, 2048 / 64), 256, 0, stream>>>(Wqkv, WqkvT, 2048, 6144);
  transpose_cvt_k<<<dim3(2048 / 64, 2048 / 64), 256, 0, stream>>>(Wout, WoutT, 2048, 2048);

  gemm_nt<0><<<dim3(48, 32), 256, 0, stream>>>(xb, WqkvT, bqkv, qws, kws, vtws, nullptr,
                                               4096, 6144, 2048);
  attn_k<<<dim3(32, 32), 256, 0, stream>>>(qws, kws, vtws, ctx);
  gemm_nt<1><<<dim3(16, 32), 256, 0, stream>>>(ctx, WoutT, bout, nullptr, nullptr, nullptr, out,
                                               4096, 2048, 2048);
}

// Round 3
// 561.654 us; speedup vs baseline: 1.8439x; 1.8439x over previous
//
#include <hip/hip_runtime.h>
#include <hip/hip_bf16.h>

typedef unsigned short ushort_t;
typedef short short8 __attribute__((ext_vector_type(8)));
typedef short short4v __attribute__((ext_vector_type(4)));
typedef float floatx4 __attribute__((ext_vector_type(4)));

#define MFMA16(a,b,c) __builtin_amdgcn_mfma_f32_16x16x32_bf16((a),(b),(c),0,0,0)

#define D_MODEL 2048
#define NHEAD   16
#define DK      128
#define SEQ     2048
#define BATCH   2

static __device__ __forceinline__ ushort_t f2bf(float f){
  union { float f; unsigned int i; } v; v.f = f;
  unsigned int r = v.i + 0x7FFFu + ((v.i >> 16) & 1u);
  return (ushort_t)(r >> 16);
}

typedef __attribute__((address_space(3))) void       lds_void_t;
typedef __attribute__((address_space(1))) const void gbl_void_t;
#define GLOAD_LDS16(g, l) \
  __builtin_amdgcn_global_load_lds((gbl_void_t*)(g), (lds_void_t*)(l), 16, 0, 0)

// ---------------- f32 -> bf16 convert (x -> xb) ----------------
__global__ __launch_bounds__(256) void cvt_k(const float* __restrict__ in,
                                             ushort_t* __restrict__ out) {
  int i = (blockIdx.x * 256 + threadIdx.x) * 8;
  floatx4 a = *(const floatx4*)&in[i];
  floatx4 b = *(const floatx4*)&in[i + 4];
  short8 r;
  for (int j = 0; j < 4; ++j) r[j] = (short)f2bf(a[j]);
  for (int j = 0; j < 4; ++j) r[4 + j] = (short)f2bf(b[j]);
  *(short8*)&out[i] = r;
}

// ---------------- transpose+convert: in f32 [R,C] -> out bf16 [C,R] ----------------
__global__ __launch_bounds__(256) void transpose_cvt_k(const float* __restrict__ in,
                                                       ushort_t* __restrict__ out,
                                                       int R, int C) {
  __shared__ ushort_t tile[64][65];
  int tr = blockIdx.y * 64, tc = blockIdx.x * 64;
  int t = threadIdx.x;
  for (int p = 0; p < 16; ++p) {
    int idx = t + p * 256;
    int r = idx >> 6, c = idx & 63;
    tile[r][c] = f2bf(in[(size_t)(tr + r) * C + (tc + c)]);
  }
  __syncthreads();
  for (int p = 0; p < 16; ++p) {
    int idx = t + p * 256;
    int r = idx >> 6, c = idx & 63;
    out[(size_t)(tc + r) * R + (tr + c)] = tile[c][r];
  }
}

// ---------------- NT GEMM (m97 structure): C = A[M,K]*BT[N,K]^T + bias ----------------
// global_load_lds width-16 staging into LINEAR LDS [128][32] per tile.
template <int MODE>
__global__ __launch_bounds__(256) void gemm_nt(const ushort_t* __restrict__ A,
                                               const ushort_t* __restrict__ BT,
                                               const float* __restrict__ bias,
                                               ushort_t* __restrict__ out_q,
                                               ushort_t* __restrict__ out_k,
                                               ushort_t* __restrict__ out_v,
                                               float* __restrict__ outp,
                                               int M, int N, int K) {
  __shared__ __align__(16) ushort_t As[128 * 32];
  __shared__ __align__(16) ushort_t Bs[128 * 32];
  const int bn = blockIdx.x, bm = blockIdx.y;
  const int t = threadIdx.x;
  const int wave = t >> 6, lane = t & 63;
  const int wr = (wave >> 1) * 64, wc = (wave & 1) * 64;
  const int l15 = lane & 15, lg = lane >> 4;
  const int row0 = bm * 128, col0 = bn * 128;

  floatx4 acc[4][4];
#pragma unroll
  for (int m = 0; m < 4; ++m)
#pragma unroll
    for (int n = 0; n < 4; ++n) acc[m][n] = (floatx4){0.f, 0.f, 0.f, 0.f};

  // staging geometry: inst (wave*2+t2) covers 16 rows; lane -> row=(lane>>2), col8=(lane&3)*8
  const int r_in = lane >> 2;
  const int c_in = (lane & 3) * 8;

  for (int k0 = 0; k0 < K; k0 += 32) {
#pragma unroll
    for (int t2 = 0; t2 < 2; ++t2) {
      int blkr = (wave * 2 + t2) * 16;
      GLOAD_LDS16(&A[(size_t)(row0 + blkr + r_in) * K + k0 + c_in], &As[blkr * 32]);
      GLOAD_LDS16(&BT[(size_t)(col0 + blkr + r_in) * K + k0 + c_in], &Bs[blkr * 32]);
    }
    __syncthreads();
    short8 af[4], bfr[4];
#pragma unroll
    for (int m = 0; m < 4; ++m) af[m]  = *(const short8*)&As[(wr + m * 16 + l15) * 32 + lg * 8];
#pragma unroll
    for (int n = 0; n < 4; ++n) bfr[n] = *(const short8*)&Bs[(wc + n * 16 + l15) * 32 + lg * 8];
#pragma unroll
    for (int m = 0; m < 4; ++m)
#pragma unroll
      for (int n = 0; n < 4; ++n)
        acc[m][n] = MFMA16(af[m], bfr[n], acc[m][n]);
    __syncthreads();
  }

  if (MODE == 1) {
#pragma unroll
    for (int m = 0; m < 4; ++m)
#pragma unroll
      for (int n = 0; n < 4; ++n) {
        int c = col0 + wc + n * 16 + l15;
        float bv = bias[c];
        int r0 = row0 + wr + m * 16 + lg * 4;
#pragma unroll
        for (int j = 0; j < 4; ++j)
          outp[(size_t)(r0 + j) * N + c] = acc[m][n][j] + bv;
      }
  } else {
    const int h = bn / 3, which = bn - h * 3;
#pragma unroll
    for (int m = 0; m < 4; ++m)
#pragma unroll
      for (int n = 0; n < 4; ++n) {
        int d = wc + n * 16 + l15;
        float bv = bias[col0 + d];
        int r0 = row0 + wr + m * 16 + lg * 4;
        int b = r0 >> 11;
        int s0 = r0 & 2047;
        if (which < 2) {
          ushort_t* dst = (which == 0) ? out_q : out_k;
          size_t base = ((size_t)(b * NHEAD + h) * SEQ) * DK;
#pragma unroll
          for (int j = 0; j < 4; ++j)
            dst[base + (size_t)(s0 + j) * DK + d] = f2bf(acc[m][n][j] + bv);
        } else {
          size_t base = ((size_t)(b * NHEAD + h) * DK + d) * SEQ + s0;
          short4v tmp;
#pragma unroll
          for (int j = 0; j < 4; ++j) tmp[j] = (short)f2bf(acc[m][n][j] + bv);
          *(short4v*)&out_v[base] = tmp;
        }
      }
  }
}

// ---------------- flash attention v2 (swapped QK^T, barrier-free) ----------------
// grid: (S/128, B*H). block 256 = 4 independent waves, each wave owns 32 q-rows.
// KV tile = 64. P staged per-wave in LDS [32 q][64 kv] bf16 with ^((row&7)<<4) swizzle.
__global__ __launch_bounds__(256, 2) void attn_k(const ushort_t* __restrict__ qws,
                                                 const ushort_t* __restrict__ kws,
                                                 const ushort_t* __restrict__ vtws,
                                                 ushort_t* __restrict__ ctx) {
  const int bh = blockIdx.y;
  const int b = bh >> 4, h = bh & 15;
  const int t = threadIdx.x, wave = t >> 6, lane = t & 63;
  const int l15 = lane & 15, lg = lane >> 4;

  const ushort_t* Q  = qws  + (size_t)bh * SEQ * DK;
  const ushort_t* Kp = kws  + (size_t)bh * SEQ * DK;
  const ushort_t* VT = vtws + (size_t)bh * DK * SEQ;

  const int qr = blockIdx.x * 128 + wave * 32;   // wave's q-row base (32 rows)

  // Q fragments (B-operand of swapped QK^T): qf[m][kk] = Q[qr+m*16+l15][kk*32+lg*8..]
  short8 qf[2][4];
#pragma unroll
  for (int m = 0; m < 2; ++m)
#pragma unroll
    for (int kk = 0; kk < 4; ++kk)
      qf[m][kk] = *(const short8*)&Q[(size_t)(qr + m * 16 + l15) * DK + kk * 32 + lg * 8];

  floatx4 o[2][8];
#pragma unroll
  for (int m = 0; m < 2; ++m)
#pragma unroll
    for (int n = 0; n < 8; ++n) o[m][n] = (floatx4){0.f, 0.f, 0.f, 0.f};
  float mrow[2] = {-1e30f, -1e30f};   // running max for q = m*16 + l15 (lane layout)
  float lrowp[2] = {0.f, 0.f};        // per-lane PARTIAL row sum (this lane's kv subset)

  __shared__ __align__(16) ushort_t P[4][32][64];
  char* Pb = (char*)&P[wave][0][0];
  const int swz = (l15 & 7) << 4;
  const float scale = 0.08838834764831845f;  // 1/sqrt(128)

  for (int kv0 = 0; kv0 < SEQ; kv0 += 64) {
    // ---- S^T = K·Q^T : D[kv][q], col=q=l15, row(kv-local)=lg*4+j ----
    floatx4 s[2][4];
#pragma unroll
    for (int m = 0; m < 2; ++m)
#pragma unroll
      for (int c = 0; c < 4; ++c) s[m][c] = (floatx4){0.f, 0.f, 0.f, 0.f};
#pragma unroll
    for (int c = 0; c < 4; ++c) {
      short8 kf[4];
#pragma unroll
      for (int kk = 0; kk < 4; ++kk)
        kf[kk] = *(const short8*)&Kp[(size_t)(kv0 + c * 16 + l15) * DK + kk * 32 + lg * 8];
#pragma unroll
      for (int m = 0; m < 2; ++m)
#pragma unroll
        for (int kk = 0; kk < 4; ++kk)
          s[m][c] = MFMA16(kf[kk], qf[m][kk], s[m][c]);
    }

    // ---- online softmax (per m-frag; lane owns q = m*16 + l15, 16 kv values) ----
#pragma unroll
    for (int m = 0; m < 2; ++m) {
      float tt[4][4];
      float rm = -1e30f;
#pragma unroll
      for (int c = 0; c < 4; ++c)
#pragma unroll
        for (int j = 0; j < 4; ++j) {
          tt[c][j] = s[m][c][j] * scale;
          rm = fmaxf(rm, tt[c][j]);
        }
      rm = fmaxf(rm, __shfl_xor(rm, 16));
      rm = fmaxf(rm, __shfl_xor(rm, 32));   // full row max across the 4 lg-lanes

      if (__any(rm > mrow[m] + 8.f)) {      // defer-max (T13)
        float rmn = fmaxf(rm, mrow[m]);
        float corr = __expf(mrow[m] - rmn);
        mrow[m] = rmn;
        lrowp[m] *= corr;
        float co[4];
#pragma unroll
        for (int j = 0; j < 4; ++j) co[j] = __shfl(corr, lg * 4 + j);
#pragma unroll
        for (int n = 0; n < 8; ++n)
#pragma unroll
          for (int j = 0; j < 4; ++j) o[m][n][j] *= co[j];
      }

      float psum = 0.f;
#pragma unroll
      for (int c = 0; c < 4; ++c) {
        float p0 = __expf(tt[c][0] - mrow[m]);
        float p1 = __expf(tt[c][1] - mrow[m]);
        float p2 = __expf(tt[c][2] - mrow[m]);
        float p3 = __expf(tt[c][3] - mrow[m]);
        psum += (p0 + p1) + (p2 + p3);
        short4v pk;
        pk[0] = (short)f2bf(p0); pk[1] = (short)f2bf(p1);
        pk[2] = (short)f2bf(p2); pk[3] = (short)f2bf(p3);
        // P[row = m*16+l15][kv = c*16 + lg*4 + 0..3], swizzled 8B packed write
        *(short4v*)(Pb + (m * 16 + l15) * 128 + ((c * 32 + lg * 8) ^ swz)) = pk;
      }
      lrowp[m] += psum;
    }

    asm volatile("s_waitcnt lgkmcnt(0)" ::: "memory");
    __builtin_amdgcn_sched_barrier(0);

    // ---- PV: O[q][d] += P[q][kv] * V[kv][d] ----
    short8 pa[2][2];
#pragma unroll
    for (int m = 0; m < 2; ++m)
#pragma unroll
      for (int ch = 0; ch < 2; ++ch)
        pa[m][ch] = *(const short8*)(Pb + (m * 16 + l15) * 128 + ((ch * 64 + lg * 16) ^ swz));
#pragma unroll
    for (int n = 0; n < 8; ++n) {
      short8 v0 = *(const short8*)&VT[(size_t)(n * 16 + l15) * SEQ + kv0 + lg * 8];
      short8 v1 = *(const short8*)&VT[(size_t)(n * 16 + l15) * SEQ + kv0 + 32 + lg * 8];
#pragma unroll
      for (int m = 0; m < 2; ++m) {
        o[m][n] = MFMA16(pa[m][0], v0, o[m][n]);
        o[m][n] = MFMA16(pa[m][1], v1, o[m][n]);
      }
    }
  }

  // ---- epilogue: finish row sums, redistribute to o layout, write ctx ----
#pragma unroll
  for (int m = 0; m < 2; ++m) {
    lrowp[m] += __shfl_xor(lrowp[m], 16);
    lrowp[m] += __shfl_xor(lrowp[m], 32);
  }
#pragma unroll
  for (int m = 0; m < 2; ++m) {
    float rcp[4];
#pragma unroll
    for (int j = 0; j < 4; ++j) rcp[j] = 1.f / __shfl(lrowp[m], lg * 4 + j);
#pragma unroll
    for (int n = 0; n < 8; ++n)
#pragma unroll
      for (int j = 0; j < 4; ++j) {
        int row = qr + m * 16 + lg * 4 + j;
        ctx[(size_t)(b * SEQ + row) * D_MODEL + h * DK + n * 16 + l15] =
            f2bf(o[m][n][j] * rcp[j]);
      }
  }
}

// ---------------- launch ----------------
extern "C" void kernel_launch(void* const* d_in, const int* in_sizes, int n_in,
                              void* d_out, int out_size, void* d_ws, size_t ws_size,
                              hipStream_t stream) {
  const float* x    = (const float*)d_in[0];
  const float* Wqkv = (const float*)d_in[1];
  const float* bqkv = (const float*)d_in[2];
  const float* Wout = (const float*)d_in[3];
  const float* bout = (const float*)d_in[4];
  float* out = (float*)d_out;

  ushort_t* WqkvT = (ushort_t*)d_ws;                         // 6144*2048
  ushort_t* WoutT = WqkvT + (size_t)6144 * 2048;             // 2048*2048
  ushort_t* qws   = WoutT + (size_t)2048 * 2048;             // [B,H,S,DK]
  ushort_t* kws   = qws + (size_t)8388608;
  ushort_t* vtws  = kws + (size_t)8388608;                   // [B,H,DK,S]
  ushort_t* ctx   = vtws + (size_t)8388608;                  // [B,S,D]
  ushort_t* xb    = ctx + (size_t)8388608;                   // [B*S, D] bf16

  cvt_k<<<4096, 256, 0, stream>>>(x, xb);
  transpose_cvt_k<<<dim3(6144 / 64, 2048 / 64), 256, 0, stream>>>(Wqkv, WqkvT, 2048, 6144);
  transpose_cvt_k<<<dim3(2048 / 64, 2048 / 64), 256, 0, stream>>>(Wout, WoutT, 2048, 2048);

  gemm_nt<0><<<dim3(48, 32), 256, 0, stream>>>(xb, WqkvT, bqkv, qws, kws, vtws, nullptr,
                                               4096, 6144, 2048);
  attn_k<<<dim3(16, 32), 256, 0, stream>>>(qws, kws, vtws, ctx);
  gemm_nt<1><<<dim3(16, 32), 256, 0, stream>>>(ctx, WoutT, bout, nullptr, nullptr, nullptr, out,
                                               4096, 2048, 2048);
}

// Round 4
// 417.266 us; speedup vs baseline: 2.4820x; 1.3460x over previous
//
#include <hip/hip_runtime.h>
#include <hip/hip_bf16.h>

typedef unsigned short ushort_t;
typedef short short8 __attribute__((ext_vector_type(8)));
typedef short short4v __attribute__((ext_vector_type(4)));
typedef float floatx4 __attribute__((ext_vector_type(4)));

#define MFMA16(a,b,c) __builtin_amdgcn_mfma_f32_16x16x32_bf16((a),(b),(c),0,0,0)

#define D_MODEL 2048
#define NHEAD   16
#define DK      128
#define SEQ     2048
#define BATCH   2

static __device__ __forceinline__ ushort_t f2bf(float f){
  union { float f; unsigned int i; } v; v.f = f;
  unsigned int r = v.i + 0x7FFFu + ((v.i >> 16) & 1u);
  return (ushort_t)(r >> 16);
}

typedef __attribute__((address_space(3))) void       lds_void_t;
typedef __attribute__((address_space(1))) const void gbl_void_t;
#define GLOAD_LDS16(g, l) \
  __builtin_amdgcn_global_load_lds((gbl_void_t*)(g), (lds_void_t*)(l), 16, 0, 0)

// ---------------- f32 -> bf16 convert (x -> xb) ----------------
__global__ __launch_bounds__(256) void cvt_k(const float* __restrict__ in,
                                             ushort_t* __restrict__ out) {
  int i = (blockIdx.x * 256 + threadIdx.x) * 8;
  floatx4 a = *(const floatx4*)&in[i];
  floatx4 b = *(const floatx4*)&in[i + 4];
  short8 r;
  for (int j = 0; j < 4; ++j) r[j] = (short)f2bf(a[j]);
  for (int j = 0; j < 4; ++j) r[4 + j] = (short)f2bf(b[j]);
  *(short8*)&out[i] = r;
}

// ---------------- transpose+convert: in f32 [R,C] -> out bf16 [C,R] ----------------
__global__ __launch_bounds__(256) void transpose_cvt_k(const float* __restrict__ in,
                                                       ushort_t* __restrict__ out,
                                                       int R, int C) {
  __shared__ ushort_t tile[64][65];
  int tr = blockIdx.y * 64, tc = blockIdx.x * 64;
  int t = threadIdx.x;
  for (int p = 0; p < 16; ++p) {
    int idx = t + p * 256;
    int r = idx >> 6, c = idx & 63;
    tile[r][c] = f2bf(in[(size_t)(tr + r) * C + (tc + c)]);
  }
  __syncthreads();
  for (int p = 0; p < 16; ++p) {
    int idx = t + p * 256;
    int r = idx >> 6, c = idx & 63;
    out[(size_t)(tc + r) * R + (tr + c)] = tile[c][r];
  }
}

// ---------------- NT GEMM (m97 structure): C = A[M,K]*BT[N,K]^T + bias ----------------
template <int MODE>
__global__ __launch_bounds__(256) void gemm_nt(const ushort_t* __restrict__ A,
                                               const ushort_t* __restrict__ BT,
                                               const float* __restrict__ bias,
                                               ushort_t* __restrict__ out_q,
                                               ushort_t* __restrict__ out_k,
                                               ushort_t* __restrict__ out_v,
                                               float* __restrict__ outp,
                                               int M, int N, int K) {
  __shared__ __align__(16) ushort_t As[128 * 32];
  __shared__ __align__(16) ushort_t Bs[128 * 32];
  const int bn = blockIdx.x, bm = blockIdx.y;
  const int t = threadIdx.x;
  const int wave = t >> 6, lane = t & 63;
  const int wr = (wave >> 1) * 64, wc = (wave & 1) * 64;
  const int l15 = lane & 15, lg = lane >> 4;
  const int row0 = bm * 128, col0 = bn * 128;

  floatx4 acc[4][4];
#pragma unroll
  for (int m = 0; m < 4; ++m)
#pragma unroll
    for (int n = 0; n < 4; ++n) acc[m][n] = (floatx4){0.f, 0.f, 0.f, 0.f};

  const int r_in = lane >> 2;
  const int c_in = (lane & 3) * 8;

  for (int k0 = 0; k0 < K; k0 += 32) {
#pragma unroll
    for (int t2 = 0; t2 < 2; ++t2) {
      int blkr = (wave * 2 + t2) * 16;
      GLOAD_LDS16(&A[(size_t)(row0 + blkr + r_in) * K + k0 + c_in], &As[blkr * 32]);
      GLOAD_LDS16(&BT[(size_t)(col0 + blkr + r_in) * K + k0 + c_in], &Bs[blkr * 32]);
    }
    __syncthreads();
    short8 af[4], bfr[4];
#pragma unroll
    for (int m = 0; m < 4; ++m) af[m]  = *(const short8*)&As[(wr + m * 16 + l15) * 32 + lg * 8];
#pragma unroll
    for (int n = 0; n < 4; ++n) bfr[n] = *(const short8*)&Bs[(wc + n * 16 + l15) * 32 + lg * 8];
#pragma unroll
    for (int m = 0; m < 4; ++m)
#pragma unroll
      for (int n = 0; n < 4; ++n)
        acc[m][n] = MFMA16(af[m], bfr[n], acc[m][n]);
    __syncthreads();
  }

  if (MODE == 1) {
#pragma unroll
    for (int m = 0; m < 4; ++m)
#pragma unroll
      for (int n = 0; n < 4; ++n) {
        int c = col0 + wc + n * 16 + l15;
        float bv = bias[c];
        int r0 = row0 + wr + m * 16 + lg * 4;
#pragma unroll
        for (int j = 0; j < 4; ++j)
          outp[(size_t)(r0 + j) * N + c] = acc[m][n][j] + bv;
      }
  } else {
    const int h = bn / 3, which = bn - h * 3;
#pragma unroll
    for (int m = 0; m < 4; ++m)
#pragma unroll
      for (int n = 0; n < 4; ++n) {
        int d = wc + n * 16 + l15;
        float bv = bias[col0 + d];
        int r0 = row0 + wr + m * 16 + lg * 4;
        int b = r0 >> 11;
        int s0 = r0 & 2047;
        if (which < 2) {
          ushort_t* dst = (which == 0) ? out_q : out_k;
          size_t base = ((size_t)(b * NHEAD + h) * SEQ) * DK;
#pragma unroll
          for (int j = 0; j < 4; ++j)
            dst[base + (size_t)(s0 + j) * DK + d] = f2bf(acc[m][n][j] + bv);
        } else {
          size_t base = ((size_t)(b * NHEAD + h) * DK + d) * SEQ + s0;
          short4v tmp;
#pragma unroll
          for (int j = 0; j < 4; ++j) tmp[j] = (short)f2bf(acc[m][n][j] + bv);
          *(short4v*)&out_v[base] = tmp;
        }
      }
  }
}

// ---------------- flash attention v3: LDS-staged K/V, double-buffered, swizzled ----------------
// grid 512 blocks. XCD-swizzled so each XCD owns 4 heads (K/V L2-resident).
// block 256 = 4 waves x 32 q-rows. KV tile 64, staged via global_load_lds (rule-21 pair).
__global__ __launch_bounds__(256, 2) void attn_k(const ushort_t* __restrict__ qws,
                                                 const ushort_t* __restrict__ kws,
                                                 const ushort_t* __restrict__ vtws,
                                                 ushort_t* __restrict__ ctx) {
  __shared__ __align__(16) ushort_t Ks[2][64 * 128];   // [kv 64][d 128], row=256B, swizzled
  __shared__ __align__(16) ushort_t Vs[2][128 * 64];   // [d 128][s 64], row=128B, swizzled
  __shared__ __align__(16) ushort_t P[4][32 * 64];     // per-wave P, row=128B, swizzled

  const int bid = blockIdx.y * gridDim.x + blockIdx.x;  // 0..511
  const int xcd = bid & 7, slot = bid >> 3;             // slot 0..63
  const int bh = xcd * 4 + (slot & 3);                  // 4 heads per XCD
  const int qt = slot >> 2;                             // 0..15
  const int b = bh >> 4, h = bh & 15;
  const int t = threadIdx.x, wave = t >> 6, lane = t & 63;
  const int l15 = lane & 15, lg = lane >> 4;

  const ushort_t* Q  = qws  + (size_t)bh * SEQ * DK;
  const ushort_t* Kp = kws  + (size_t)bh * SEQ * DK;
  const ushort_t* VT = vtws + (size_t)bh * DK * SEQ;

  const int qr = qt * 128 + wave * 32;   // wave's q-row base (32 rows)

  short8 qf[2][4];
#pragma unroll
  for (int m = 0; m < 2; ++m)
#pragma unroll
    for (int kk = 0; kk < 4; ++kk)
      qf[m][kk] = *(const short8*)&Q[(size_t)(qr + m * 16 + l15) * DK + kk * 32 + lg * 8];

  floatx4 o[2][8];
#pragma unroll
  for (int m = 0; m < 2; ++m)
#pragma unroll
    for (int n = 0; n < 8; ++n) o[m][n] = (floatx4){0.f, 0.f, 0.f, 0.f};
  float mrow[2] = {-1e30f, -1e30f};
  float lrowp[2] = {0.f, 0.f};

  char* Pb = (char*)&P[wave][0];
  const int swz = (l15 & 7) << 4;
  const float scale = 0.08838834764831845f;  // 1/sqrt(128)

  // stage: K rows wave*16..+16 (4 insts x 1KB), V rows wave*32..+32 (4 insts x 1KB)
  // LDS linear dest + inverse-swizzled global source (rule 21).
  auto STAGE = [&](int buf, int kv0) {
#pragma unroll
    for (int t2 = 0; t2 < 4; ++t2) {
      int rowK = wave * 16 + t2 * 4 + (lane >> 4);
      int csK = ((lane & 15) * 16) ^ ((rowK & 7) << 4);
      GLOAD_LDS16((const char*)&Kp[(size_t)(kv0 + rowK) * DK] + csK,
                  (char*)&Ks[buf][0] + wave * 4096 + t2 * 1024);
      int rowV = wave * 32 + t2 * 8 + (lane >> 3);
      int csV = ((lane & 7) * 16) ^ ((rowV & 7) << 4);
      GLOAD_LDS16((const char*)&VT[(size_t)rowV * SEQ + kv0] + csV,
                  (char*)&Vs[buf][0] + wave * 4096 + t2 * 1024);
    }
  };

  STAGE(0, 0);
  __syncthreads();

  for (int it = 0; it < SEQ / 64; ++it) {
    const char* KsC = (const char*)&Ks[it & 1][0];
    const char* VsC = (const char*)&Vs[it & 1][0];
    if (it < SEQ / 64 - 1) STAGE((it + 1) & 1, (it + 1) * 64);

    // ---- S^T = K·Q^T from LDS (swizzled reads) ----
    floatx4 s[2][4];
#pragma unroll
    for (int m = 0; m < 2; ++m)
#pragma unroll
      for (int c = 0; c < 4; ++c) s[m][c] = (floatx4){0.f, 0.f, 0.f, 0.f};
#pragma unroll
    for (int c = 0; c < 4; ++c) {
      short8 kf[4];
#pragma unroll
      for (int kk = 0; kk < 4; ++kk)
        kf[kk] = *(const short8*)(KsC + (c * 16 + l15) * 256 + ((kk * 64 + lg * 16) ^ swz));
#pragma unroll
      for (int m = 0; m < 2; ++m)
#pragma unroll
        for (int kk = 0; kk < 4; ++kk)
          s[m][c] = MFMA16(kf[kk], qf[m][kk], s[m][c]);
    }

    // ---- online softmax ----
#pragma unroll
    for (int m = 0; m < 2; ++m) {
      float tt[4][4];
      float rm = -1e30f;
#pragma unroll
      for (int c = 0; c < 4; ++c)
#pragma unroll
        for (int j = 0; j < 4; ++j) {
          tt[c][j] = s[m][c][j] * scale;
          rm = fmaxf(rm, tt[c][j]);
        }
      rm = fmaxf(rm, __shfl_xor(rm, 16));
      rm = fmaxf(rm, __shfl_xor(rm, 32));

      if (__any(rm > mrow[m] + 8.f)) {      // defer-max (T13)
        float rmn = fmaxf(rm, mrow[m]);
        float corr = __expf(mrow[m] - rmn);
        mrow[m] = rmn;
        lrowp[m] *= corr;
        float co[4];
#pragma unroll
        for (int j = 0; j < 4; ++j) co[j] = __shfl(corr, lg * 4 + j);
#pragma unroll
        for (int n = 0; n < 8; ++n)
#pragma unroll
          for (int j = 0; j < 4; ++j) o[m][n][j] *= co[j];
      }

      float psum = 0.f;
#pragma unroll
      for (int c = 0; c < 4; ++c) {
        float p0 = __expf(tt[c][0] - mrow[m]);
        float p1 = __expf(tt[c][1] - mrow[m]);
        float p2 = __expf(tt[c][2] - mrow[m]);
        float p3 = __expf(tt[c][3] - mrow[m]);
        psum += (p0 + p1) + (p2 + p3);
        short4v pk;
        pk[0] = (short)f2bf(p0); pk[1] = (short)f2bf(p1);
        pk[2] = (short)f2bf(p2); pk[3] = (short)f2bf(p3);
        *(short4v*)(Pb + (m * 16 + l15) * 128 + ((c * 32 + lg * 8) ^ swz)) = pk;
      }
      lrowp[m] += psum;
    }

    asm volatile("s_waitcnt lgkmcnt(0)" ::: "memory");
    __builtin_amdgcn_sched_barrier(0);

    // ---- PV from LDS (swizzled reads) ----
    short8 pa[2][2];
#pragma unroll
    for (int m = 0; m < 2; ++m)
#pragma unroll
      for (int ch = 0; ch < 2; ++ch)
        pa[m][ch] = *(const short8*)(Pb + (m * 16 + l15) * 128 + ((ch * 64 + lg * 16) ^ swz));
#pragma unroll
    for (int n = 0; n < 8; ++n) {
      short8 v0 = *(const short8*)(VsC + (n * 16 + l15) * 128 + ((lg * 16) ^ swz));
      short8 v1 = *(const short8*)(VsC + (n * 16 + l15) * 128 + ((64 + lg * 16) ^ swz));
#pragma unroll
      for (int m = 0; m < 2; ++m) {
        o[m][n] = MFMA16(pa[m][0], v0, o[m][n]);
        o[m][n] = MFMA16(pa[m][1], v1, o[m][n]);
      }
    }
    __syncthreads();   // drains vmcnt: next tile staged; cur tile free for overwrite
  }

  // ---- epilogue ----
#pragma unroll
  for (int m = 0; m < 2; ++m) {
    lrowp[m] += __shfl_xor(lrowp[m], 16);
    lrowp[m] += __shfl_xor(lrowp[m], 32);
  }
#pragma unroll
  for (int m = 0; m < 2; ++m) {
    float rcp[4];
#pragma unroll
    for (int j = 0; j < 4; ++j) rcp[j] = 1.f / __shfl(lrowp[m], lg * 4 + j);
#pragma unroll
    for (int n = 0; n < 8; ++n)
#pragma unroll
      for (int j = 0; j < 4; ++j) {
        int row = qr + m * 16 + lg * 4 + j;
        ctx[(size_t)(b * SEQ + row) * D_MODEL + h * DK + n * 16 + l15] =
            f2bf(o[m][n][j] * rcp[j]);
      }
  }
}

// ---------------- launch ----------------
extern "C" void kernel_launch(void* const* d_in, const int* in_sizes, int n_in,
                              void* d_out, int out_size, void* d_ws, size_t ws_size,
                              hipStream_t stream) {
  const float* x    = (const float*)d_in[0];
  const float* Wqkv = (const float*)d_in[1];
  const float* bqkv = (const float*)d_in[2];
  const float* Wout = (const float*)d_in[3];
  const float* bout = (const float*)d_in[4];
  float* out = (float*)d_out;

  ushort_t* WqkvT = (ushort_t*)d_ws;                         // 6144*2048
  ushort_t* WoutT = WqkvT + (size_t)6144 * 2048;             // 2048*2048
  ushort_t* qws   = WoutT + (size_t)2048 * 2048;             // [B,H,S,DK]
  ushort_t* kws   = qws + (size_t)8388608;
  ushort_t* vtws  = kws + (size_t)8388608;                   // [B,H,DK,S]
  ushort_t* ctx   = vtws + (size_t)8388608;                  // [B,S,D]
  ushort_t* xb    = ctx + (size_t)8388608;                   // [B*S, D] bf16

  cvt_k<<<4096, 256, 0, stream>>>(x, xb);
  transpose_cvt_k<<<dim3(6144 / 64, 2048 / 64), 256, 0, stream>>>(Wqkv, WqkvT, 2048, 6144);
  transpose_cvt_k<<<dim3(2048 / 64, 2048 / 64), 256, 0, stream>>>(Wout, WoutT, 2048, 2048);

  gemm_nt<0><<<dim3(48, 32), 256, 0, stream>>>(xb, WqkvT, bqkv, qws, kws, vtws, nullptr,
                                               4096, 6144, 2048);
  attn_k<<<dim3(16, 32), 256, 0, stream>>>(qws, kws, vtws, ctx);
  gemm_nt<1><<<dim3(16, 32), 256, 0, stream>>>(ctx, WoutT, bout, nullptr, nullptr, nullptr, out,
                                               4096, 2048, 2048);
}

// Round 6
// 397.498 us; speedup vs baseline: 2.6054x; 1.0497x over previous
//
#include <hip/hip_runtime.h>
#include <hip/hip_bf16.h>

typedef unsigned short ushort_t;
typedef short short8 __attribute__((ext_vector_type(8)));
typedef short short4v __attribute__((ext_vector_type(4)));
typedef float floatx4 __attribute__((ext_vector_type(4)));

#define MFMA16(a,b,c) __builtin_amdgcn_mfma_f32_16x16x32_bf16((a),(b),(c),0,0,0)

#define D_MODEL 2048
#define NHEAD   16
#define DK      128
#define SEQ     2048
#define BATCH   2

static __device__ __forceinline__ ushort_t f2bf(float f){
  union { float f; unsigned int i; } v; v.f = f;
  unsigned int r = v.i + 0x7FFFu + ((v.i >> 16) & 1u);
  return (ushort_t)(r >> 16);
}

typedef __attribute__((address_space(3))) void       lds_void_t;
typedef __attribute__((address_space(1))) const void gbl_void_t;
#define GLOAD_LDS16(g, l) \
  __builtin_amdgcn_global_load_lds((gbl_void_t*)(g), (lds_void_t*)(l), 16, 0, 0)

// ---------------- f32 -> bf16 convert (x -> xb) ----------------
__global__ __launch_bounds__(256) void cvt_k(const float* __restrict__ in,
                                             ushort_t* __restrict__ out) {
  int i = (blockIdx.x * 256 + threadIdx.x) * 8;
  floatx4 a = *(const floatx4*)&in[i];
  floatx4 b = *(const floatx4*)&in[i + 4];
  short8 r;
  for (int j = 0; j < 4; ++j) r[j] = (short)f2bf(a[j]);
  for (int j = 0; j < 4; ++j) r[4 + j] = (short)f2bf(b[j]);
  *(short8*)&out[i] = r;
}

// ---------------- transpose+convert: in f32 [R,C] -> out bf16 [C,R] ----------------
__global__ __launch_bounds__(256) void transpose_cvt_k(const float* __restrict__ in,
                                                       ushort_t* __restrict__ out,
                                                       int R, int C) {
  __shared__ ushort_t tile[64][65];
  int tr = blockIdx.y * 64, tc = blockIdx.x * 64;
  int t = threadIdx.x;
  for (int p = 0; p < 16; ++p) {
    int idx = t + p * 256;
    int r = idx >> 6, c = idx & 63;
    tile[r][c] = f2bf(in[(size_t)(tr + r) * C + (tc + c)]);
  }
  __syncthreads();
  for (int p = 0; p < 16; ++p) {
    int idx = t + p * 256;
    int r = idx >> 6, c = idx & 63;
    out[(size_t)(tc + r) * R + (tr + c)] = tile[c][r];
  }
}

// ---------------- phased NT GEMM: BM=128, BN=256, BK=64, 8 waves (2x4), K=2048 ----------
// 2 phases per K-tile: {8 ds_read_b128 | stage next tile | barrier; lgkmcnt(0); 16 MFMA}.
// Double-buffered LDS, row-XOR swizzle (rule 21: linear LDS dest + inverse-swizzled
// global source + swizzled ds_read). XCD-chunked block swizzle.
// MODE 0: QKV projection -> scatter q/k/vT.  MODE 1: out-proj -> f32.
template <int MODE>
__global__ __launch_bounds__(512, 1) void gemm8p(const ushort_t* __restrict__ A,
                                                 const ushort_t* __restrict__ BT,
                                                 const float* __restrict__ bias,
                                                 ushort_t* __restrict__ out_q,
                                                 ushort_t* __restrict__ out_k,
                                                 ushort_t* __restrict__ out_v,
                                                 float* __restrict__ outp,
                                                 int N, int nbn) {
  __shared__ __align__(16) ushort_t As[2][128 * 64];   // 2 x 16 KB
  __shared__ __align__(16) ushort_t Bs[2][256 * 64];   // 2 x 32 KB

  const int nwg = gridDim.x;
  const int orig = blockIdx.x;
  const int wg = (orig & 7) * (nwg >> 3) + (orig >> 3);   // XCD-chunked (nwg % 8 == 0)
  const int bm = wg / nbn, bn = wg - bm * nbn;
  const int row0 = bm * 128, col0 = bn * 256;

  const int t = threadIdx.x, wave = t >> 6, lane = t & 63;
  const int wm = wave >> 2, wn = wave & 3;
  const int l15 = lane & 15, lg = lane >> 4;
  const int swz = (l15 & 7) << 4;
  const int csrc = ((lane & 7) * 16) ^ ((lane >> 3) << 4);  // inverse-swizzled source bytes
  const int rsub = lane >> 3;                               // row within 8-row stage block

  char* AsC = (char*)&As[0][0];
  char* BsC = (char*)&Bs[0][0];

  floatx4 acc[4][4];
#pragma unroll
  for (int m = 0; m < 4; ++m)
#pragma unroll
    for (int n = 0; n < 4; ++n) acc[m][n] = (floatx4){0.f, 0.f, 0.f, 0.f};

#define STAGE_A(buf, k0, j) \
  GLOAD_LDS16((const char*)&A[(size_t)(row0 + (j) * 64 + wave * 8 + rsub) * 2048 + (k0)] + csrc, \
              AsC + (buf) * 16384 + ((j) * 64 + wave * 8) * 128)
#define STAGE_B(buf, k0, j) \
  GLOAD_LDS16((const char*)&BT[(size_t)(col0 + (j) * 64 + wave * 8 + rsub) * 2048 + (k0)] + csrc, \
              BsC + (buf) * 32768 + ((j) * 64 + wave * 8) * 128)

  // prologue: stage K-tile 0 into buf 0
  STAGE_A(0, 0, 0); STAGE_A(0, 0, 1);
  STAGE_B(0, 0, 0); STAGE_B(0, 0, 1); STAGE_B(0, 0, 2); STAGE_B(0, 0, 3);
  asm volatile("s_waitcnt vmcnt(0)" ::: "memory");
  __builtin_amdgcn_s_barrier();

  for (int kt = 0; kt < 32; ++kt) {
    const int buf = kt & 1, nb = buf ^ 1;
    const int nk0 = (kt + 1) * 64;
    const char* Ab = AsC + buf * 16384;
    const char* Bb = BsC + buf * 32768;
    short8 a[4], b[4];

    // ---- phase 0 (kk = 0) ----
#pragma unroll
    for (int m = 0; m < 4; ++m)
      a[m] = *(const short8*)(Ab + (wm * 64 + m * 16 + l15) * 128 + ((lg * 16) ^ swz));
#pragma unroll
    for (int n = 0; n < 4; ++n)
      b[n] = *(const short8*)(Bb + (wn * 64 + n * 16 + l15) * 128 + ((lg * 16) ^ swz));
    if (kt < 31) {
      STAGE_A(nb, nk0, 0); STAGE_A(nb, nk0, 1);
      STAGE_B(nb, nk0, 0); STAGE_B(nb, nk0, 1);
    }
    __builtin_amdgcn_s_barrier();
    asm volatile("s_waitcnt lgkmcnt(0)" ::: "memory");
    __builtin_amdgcn_sched_barrier(0);
    __builtin_amdgcn_s_setprio(1);
#pragma unroll
    for (int m = 0; m < 4; ++m)
#pragma unroll
      for (int n = 0; n < 4; ++n)
        acc[m][n] = MFMA16(a[m], b[n], acc[m][n]);
    __builtin_amdgcn_s_setprio(0);
    __builtin_amdgcn_s_barrier();

    // ---- phase 1 (kk = 1) ----
#pragma unroll
    for (int m = 0; m < 4; ++m)
      a[m] = *(const short8*)(Ab + (wm * 64 + m * 16 + l15) * 128 + ((64 + lg * 16) ^ swz));
#pragma unroll
    for (int n = 0; n < 4; ++n)
      b[n] = *(const short8*)(Bb + (wn * 64 + n * 16 + l15) * 128 + ((64 + lg * 16) ^ swz));
    if (kt < 31) {
      STAGE_B(nb, nk0, 2); STAGE_B(nb, nk0, 3);
    }
    __builtin_amdgcn_s_barrier();
    asm volatile("s_waitcnt lgkmcnt(0)" ::: "memory");
    __builtin_amdgcn_sched_barrier(0);
    __builtin_amdgcn_s_setprio(1);
#pragma unroll
    for (int m = 0; m < 4; ++m)
#pragma unroll
      for (int n = 0; n < 4; ++n)
        acc[m][n] = MFMA16(a[m], b[n], acc[m][n]);
    __builtin_amdgcn_s_setprio(0);
    asm volatile("s_waitcnt vmcnt(0)" ::: "memory");   // next tile fully staged
    __builtin_amdgcn_s_barrier();
  }
#undef STAGE_A
#undef STAGE_B

  // ---- epilogue ----
  if (MODE == 1) {
#pragma unroll
    for (int m = 0; m < 4; ++m)
#pragma unroll
      for (int n = 0; n < 4; ++n) {
        int c = col0 + wn * 64 + n * 16 + l15;
        float bv = bias[c];
        int r0 = row0 + wm * 64 + m * 16 + lg * 4;
#pragma unroll
        for (int j = 0; j < 4; ++j)
          outp[(size_t)(r0 + j) * N + c] = acc[m][n][j] + bv;
      }
  } else {
#pragma unroll
    for (int m = 0; m < 4; ++m)
#pragma unroll
      for (int n = 0; n < 4; ++n) {
        int c = col0 + wn * 64 + n * 16 + l15;
        float bv = bias[c];
        int blk = c >> 7;                 // 128-col block: head h gets blocks 3h..3h+2
        int h = blk / 3, which = blk - h * 3;
        int d = c & 127;
        int r0 = row0 + wm * 64 + m * 16 + lg * 4;
        int b = r0 >> 11;
        int s0 = r0 & 2047;
        if (which < 2) {
          ushort_t* dst = (which == 0) ? out_q : out_k;
          size_t base = ((size_t)(b * NHEAD + h) * SEQ) * DK;
#pragma unroll
          for (int j = 0; j < 4; ++j)
            dst[base + (size_t)(s0 + j) * DK + d] = f2bf(acc[m][n][j] + bv);
        } else {
          size_t base = ((size_t)(b * NHEAD + h) * DK + d) * SEQ + s0;
          short4v tmp;
#pragma unroll
          for (int j = 0; j < 4; ++j) tmp[j] = (short)f2bf(acc[m][n][j] + bv);
          *(short4v*)&out_v[base] = tmp;
        }
      }
  }
}

// ---------------- flash attention: LDS-staged K/V, double-buffered, swizzled ----------------
__global__ __launch_bounds__(256, 2) void attn_k(const ushort_t* __restrict__ qws,
                                                 const ushort_t* __restrict__ kws,
                                                 const ushort_t* __restrict__ vtws,
                                                 ushort_t* __restrict__ ctx) {
  __shared__ __align__(16) ushort_t Ks[2][64 * 128];
  __shared__ __align__(16) ushort_t Vs[2][128 * 64];
  __shared__ __align__(16) ushort_t P[4][32 * 64];

  const int bid = blockIdx.y * gridDim.x + blockIdx.x;
  const int xcd = bid & 7, slot = bid >> 3;
  const int bh = xcd * 4 + (slot & 3);
  const int qt = slot >> 2;
  const int b = bh >> 4, h = bh & 15;
  const int t = threadIdx.x, wave = t >> 6, lane = t & 63;
  const int l15 = lane & 15, lg = lane >> 4;

  const ushort_t* Q  = qws  + (size_t)bh * SEQ * DK;
  const ushort_t* Kp = kws  + (size_t)bh * SEQ * DK;
  const ushort_t* VT = vtws + (size_t)bh * DK * SEQ;

  const int qr = qt * 128 + wave * 32;

  short8 qf[2][4];
#pragma unroll
  for (int m = 0; m < 2; ++m)
#pragma unroll
    for (int kk = 0; kk < 4; ++kk)
      qf[m][kk] = *(const short8*)&Q[(size_t)(qr + m * 16 + l15) * DK + kk * 32 + lg * 8];

  floatx4 o[2][8];
#pragma unroll
  for (int m = 0; m < 2; ++m)
#pragma unroll
    for (int n = 0; n < 8; ++n) o[m][n] = (floatx4){0.f, 0.f, 0.f, 0.f};
  float mrow[2] = {-1e30f, -1e30f};
  float lrowp[2] = {0.f, 0.f};

  char* Pb = (char*)&P[wave][0];
  const int swz = (l15 & 7) << 4;
  const float scale = 0.08838834764831845f;

  auto STAGE = [&](int buf, int kv0) {
#pragma unroll
    for (int t2 = 0; t2 < 4; ++t2) {
      int rowK = wave * 16 + t2 * 4 + (lane >> 4);
      int csK = ((lane & 15) * 16) ^ ((rowK & 7) << 4);
      GLOAD_LDS16((const char*)&Kp[(size_t)(kv0 + rowK) * DK] + csK,
                  (char*)&Ks[buf][0] + wave * 4096 + t2 * 1024);
      int rowV = wave * 32 + t2 * 8 + (lane >> 3);
      int csV = ((lane & 7) * 16) ^ ((rowV & 7) << 4);
      GLOAD_LDS16((const char*)&VT[(size_t)rowV * SEQ + kv0] + csV,
                  (char*)&Vs[buf][0] + wave * 4096 + t2 * 1024);
    }
  };

  STAGE(0, 0);
  __syncthreads();

  for (int it = 0; it < SEQ / 64; ++it) {
    const char* KsC = (const char*)&Ks[it & 1][0];
    const char* VsC = (const char*)&Vs[it & 1][0];
    if (it < SEQ / 64 - 1) STAGE((it + 1) & 1, (it + 1) * 64);

    floatx4 s[2][4];
#pragma unroll
    for (int m = 0; m < 2; ++m)
#pragma unroll
      for (int c = 0; c < 4; ++c) s[m][c] = (floatx4){0.f, 0.f, 0.f, 0.f};
#pragma unroll
    for (int c = 0; c < 4; ++c) {
      short8 kf[4];
#pragma unroll
      for (int kk = 0; kk < 4; ++kk)
        kf[kk] = *(const short8*)(KsC + (c * 16 + l15) * 256 + ((kk * 64 + lg * 16) ^ swz));
#pragma unroll
      for (int m = 0; m < 2; ++m)
#pragma unroll
        for (int kk = 0; kk < 4; ++kk)
          s[m][c] = MFMA16(kf[kk], qf[m][kk], s[m][c]);
    }

#pragma unroll
    for (int m = 0; m < 2; ++m) {
      float tt[4][4];
      float rm = -1e30f;
#pragma unroll
      for (int c = 0; c < 4; ++c)
#pragma unroll
        for (int j = 0; j < 4; ++j) {
          tt[c][j] = s[m][c][j] * scale;
          rm = fmaxf(rm, tt[c][j]);
        }
      rm = fmaxf(rm, __shfl_xor(rm, 16));
      rm = fmaxf(rm, __shfl_xor(rm, 32));

      if (__any(rm > mrow[m] + 8.f)) {
        float rmn = fmaxf(rm, mrow[m]);
        float corr = __expf(mrow[m] - rmn);
        mrow[m] = rmn;
        lrowp[m] *= corr;
        float co[4];
#pragma unroll
        for (int j = 0; j < 4; ++j) co[j] = __shfl(corr, lg * 4 + j);
#pragma unroll
        for (int n = 0; n < 8; ++n)
#pragma unroll
          for (int j = 0; j < 4; ++j) o[m][n][j] *= co[j];
      }

      float psum = 0.f;
#pragma unroll
      for (int c = 0; c < 4; ++c) {
        float p0 = __expf(tt[c][0] - mrow[m]);
        float p1 = __expf(tt[c][1] - mrow[m]);
        float p2 = __expf(tt[c][2] - mrow[m]);
        float p3 = __expf(tt[c][3] - mrow[m]);
        psum += (p0 + p1) + (p2 + p3);
        short4v pk;
        pk[0] = (short)f2bf(p0); pk[1] = (short)f2bf(p1);
        pk[2] = (short)f2bf(p2); pk[3] = (short)f2bf(p3);
        *(short4v*)(Pb + (m * 16 + l15) * 128 + ((c * 32 + lg * 8) ^ swz)) = pk;
      }
      lrowp[m] += psum;
    }

    asm volatile("s_waitcnt lgkmcnt(0)" ::: "memory");
    __builtin_amdgcn_sched_barrier(0);

    short8 pa[2][2];
#pragma unroll
    for (int m = 0; m < 2; ++m)
#pragma unroll
      for (int ch = 0; ch < 2; ++ch)
        pa[m][ch] = *(const short8*)(Pb + (m * 16 + l15) * 128 + ((ch * 64 + lg * 16) ^ swz));
#pragma unroll
    for (int n = 0; n < 8; ++n) {
      short8 v0 = *(const short8*)(VsC + (n * 16 + l15) * 128 + ((lg * 16) ^ swz));
      short8 v1 = *(const short8*)(VsC + (n * 16 + l15) * 128 + ((64 + lg * 16) ^ swz));
#pragma unroll
      for (int m = 0; m < 2; ++m) {
        o[m][n] = MFMA16(pa[m][0], v0, o[m][n]);
        o[m][n] = MFMA16(pa[m][1], v1, o[m][n]);
      }
    }
    __syncthreads();
  }

#pragma unroll
  for (int m = 0; m < 2; ++m) {
    lrowp[m] += __shfl_xor(lrowp[m], 16);
    lrowp[m] += __shfl_xor(lrowp[m], 32);
  }
#pragma unroll
  for (int m = 0; m < 2; ++m) {
    float rcp[4];
#pragma unroll
    for (int j = 0; j < 4; ++j) rcp[j] = 1.f / __shfl(lrowp[m], lg * 4 + j);
#pragma unroll
    for (int n = 0; n < 8; ++n)
#pragma unroll
      for (int j = 0; j < 4; ++j) {
        int row = qr + m * 16 + lg * 4 + j;
        ctx[(size_t)(b * SEQ + row) * D_MODEL + h * DK + n * 16 + l15] =
            f2bf(o[m][n][j] * rcp[j]);
      }
  }
}

// ---------------- launch ----------------
extern "C" void kernel_launch(void* const* d_in, const int* in_sizes, int n_in,
                              void* d_out, int out_size, void* d_ws, size_t ws_size,
                              hipStream_t stream) {
  const float* x    = (const float*)d_in[0];
  const float* Wqkv = (const float*)d_in[1];
  const float* bqkv = (const float*)d_in[2];
  const float* Wout = (const float*)d_in[3];
  const float* bout = (const float*)d_in[4];
  float* out = (float*)d_out;

  ushort_t* WqkvT = (ushort_t*)d_ws;
  ushort_t* WoutT = WqkvT + (size_t)6144 * 2048;
  ushort_t* qws   = WoutT + (size_t)2048 * 2048;
  ushort_t* kws   = qws + (size_t)8388608;
  ushort_t* vtws  = kws + (size_t)8388608;
  ushort_t* ctx   = vtws + (size_t)8388608;
  ushort_t* xb    = ctx + (size_t)8388608;

  cvt_k<<<4096, 256, 0, stream>>>(x, xb);
  transpose_cvt_k<<<dim3(6144 / 64, 2048 / 64), 256, 0, stream>>>(Wqkv, WqkvT, 2048, 6144);
  transpose_cvt_k<<<dim3(2048 / 64, 2048 / 64), 256, 0, stream>>>(Wout, WoutT, 2048, 2048);

  gemm8p<0><<<768, 512, 0, stream>>>(xb, WqkvT, bqkv, qws, kws, vtws, nullptr, 6144, 24);
  attn_k<<<dim3(16, 32), 256, 0, stream>>>(qws, kws, vtws, ctx);
  gemm8p<1><<<256, 512, 0, stream>>>(ctx, WoutT, bout, nullptr, nullptr, nullptr, out, 2048, 8);
}

// Round 7
// 396.680 us; speedup vs baseline: 2.6108x; 1.0021x over previous
//
#include <hip/hip_runtime.h>
#include <hip/hip_bf16.h>

typedef unsigned short ushort_t;
typedef short short8 __attribute__((ext_vector_type(8)));
typedef short short4v __attribute__((ext_vector_type(4)));
typedef float floatx4 __attribute__((ext_vector_type(4)));

#define MFMA16(a,b,c) __builtin_amdgcn_mfma_f32_16x16x32_bf16((a),(b),(c),0,0,0)

#define D_MODEL 2048
#define NHEAD   16
#define DK      128
#define SEQ     2048
#define BATCH   2

static __device__ __forceinline__ ushort_t f2bf(float f){
  union { float f; unsigned int i; } v; v.f = f;
  unsigned int r = v.i + 0x7FFFu + ((v.i >> 16) & 1u);
  return (ushort_t)(r >> 16);
}

typedef __attribute__((address_space(3))) void       lds_void_t;
typedef __attribute__((address_space(1))) const void gbl_void_t;
#define GLOAD_LDS16(g, l) \
  __builtin_amdgcn_global_load_lds((gbl_void_t*)(g), (lds_void_t*)(l), 16, 0, 0)

// ---------------- f32 -> bf16 convert (x -> xb) ----------------
__global__ __launch_bounds__(256) void cvt_k(const float* __restrict__ in,
                                             ushort_t* __restrict__ out) {
  int i = (blockIdx.x * 256 + threadIdx.x) * 8;
  floatx4 a = *(const floatx4*)&in[i];
  floatx4 b = *(const floatx4*)&in[i + 4];
  short8 r;
  for (int j = 0; j < 4; ++j) r[j] = (short)f2bf(a[j]);
  for (int j = 0; j < 4; ++j) r[4 + j] = (short)f2bf(b[j]);
  *(short8*)&out[i] = r;
}

// ---------------- transpose+convert: in f32 [R,C] -> out bf16 [C,R] ----------------
__global__ __launch_bounds__(256) void transpose_cvt_k(const float* __restrict__ in,
                                                       ushort_t* __restrict__ out,
                                                       int R, int C) {
  __shared__ ushort_t tile[64][65];
  int tr = blockIdx.y * 64, tc = blockIdx.x * 64;
  int t = threadIdx.x;
  for (int p = 0; p < 16; ++p) {
    int idx = t + p * 256;
    int r = idx >> 6, c = idx & 63;
    tile[r][c] = f2bf(in[(size_t)(tr + r) * C + (tc + c)]);
  }
  __syncthreads();
  for (int p = 0; p < 16; ++p) {
    int idx = t + p * 256;
    int r = idx >> 6, c = idx & 63;
    out[(size_t)(tc + r) * R + (tr + c)] = tile[c][r];
  }
}

// -------- phased NT GEMM: BM=128, BN=256, BK=64, 8 waves (2x4), K=2048 --------
// 3-buffer LDS rotation, depth-2 prefetch, COUNTED vmcnt(6) (T4): tile t+2's
// 6 loads/wave issued during tile t; tile-end wait = "<=6 outstanding" => tile
// t+1 landed, t+2 in flight. Row-XOR swizzle both sides (rule 21), XCD-chunked.
// MODE 0: QKV projection -> scatter q/k/vT.  MODE 1: out-proj -> f32.
template <int MODE>
__global__ __launch_bounds__(512, 1) void gemm8p(const ushort_t* __restrict__ A,
                                                 const ushort_t* __restrict__ BT,
                                                 const float* __restrict__ bias,
                                                 ushort_t* __restrict__ out_q,
                                                 ushort_t* __restrict__ out_k,
                                                 ushort_t* __restrict__ out_v,
                                                 float* __restrict__ outp,
                                                 int N, int nbn) {
  // per buffer: A 128x64 (16 KB) + B 256x64 (32 KB) = 48 KB; 3 buffers = 144 KB
  __shared__ __align__(16) ushort_t lds[3 * 24576];

  const int nwg = gridDim.x;
  const int orig = blockIdx.x;
  const int wg = (orig & 7) * (nwg >> 3) + (orig >> 3);   // XCD-chunked (nwg % 8 == 0)
  const int bm = wg / nbn, bn = wg - bm * nbn;
  const int row0 = bm * 128, col0 = bn * 256;

  const int t = threadIdx.x, wave = t >> 6, lane = t & 63;
  const int wm = wave >> 2, wn = wave & 3;
  const int l15 = lane & 15, lg = lane >> 4;
  const int swz = (l15 & 7) << 4;
  const int csrc = ((lane & 7) * 16) ^ ((lane >> 3) << 4);  // inverse-swizzled source bytes
  const int rsub = lane >> 3;                               // row within 8-row stage block

  char* buf0 = (char*)&lds[0];
  char* buf1 = buf0 + 49152;
  char* buf2 = buf1 + 49152;

  floatx4 acc[4][4];
#pragma unroll
  for (int m = 0; m < 4; ++m)
#pragma unroll
    for (int n = 0; n < 4; ++n) acc[m][n] = (floatx4){0.f, 0.f, 0.f, 0.f};

  // A occupies bytes [0, 16384), B occupies [16384, 49152) of each buffer.
#define STAGE_A(dst, k0, j) \
  GLOAD_LDS16((const char*)&A[(size_t)(row0 + (j) * 64 + wave * 8 + rsub) * 2048 + (k0)] + csrc, \
              (dst) + ((j) * 64 + wave * 8) * 128)
#define STAGE_B(dst, k0, j) \
  GLOAD_LDS16((const char*)&BT[(size_t)(col0 + (j) * 64 + wave * 8 + rsub) * 2048 + (k0)] + csrc, \
              (dst) + 16384 + ((j) * 64 + wave * 8) * 128)
#define STAGE_ALL(dst, k0) \
  do { STAGE_A(dst, k0, 0); STAGE_A(dst, k0, 1); \
       STAGE_B(dst, k0, 0); STAGE_B(dst, k0, 1); STAGE_B(dst, k0, 2); STAGE_B(dst, k0, 3); } while (0)

  // prologue: stage tiles 0 and 1; wait until tile 0 landed (<=6 outstanding)
  STAGE_ALL(buf0, 0);
  STAGE_ALL(buf1, 64);
  asm volatile("s_waitcnt vmcnt(6)" ::: "memory");
  __builtin_amdgcn_s_barrier();

  char* cur = buf0;
  char* nxt = buf1;
  char* stg = buf2;

  for (int kt = 0; kt < 32; ++kt) {
    const int sk0 = (kt + 2) * 64;
    const bool stage = (kt < 30);
    short8 a[4], b[4];

    // ---- phase 0 (kk = 0) ----
#pragma unroll
    for (int m = 0; m < 4; ++m)
      a[m] = *(const short8*)(cur + (wm * 64 + m * 16 + l15) * 128 + ((lg * 16) ^ swz));
#pragma unroll
    for (int n = 0; n < 4; ++n)
      b[n] = *(const short8*)(cur + 16384 + (wn * 64 + n * 16 + l15) * 128 + ((lg * 16) ^ swz));
    if (stage) {
      STAGE_A(stg, sk0, 0); STAGE_A(stg, sk0, 1); STAGE_B(stg, sk0, 0);
    }
    __builtin_amdgcn_s_barrier();
    asm volatile("s_waitcnt lgkmcnt(0)" ::: "memory");
    __builtin_amdgcn_sched_barrier(0);
    __builtin_amdgcn_s_setprio(1);
#pragma unroll
    for (int m = 0; m < 4; ++m)
#pragma unroll
      for (int n = 0; n < 4; ++n)
        acc[m][n] = MFMA16(a[m], b[n], acc[m][n]);
    __builtin_amdgcn_s_setprio(0);
    __builtin_amdgcn_s_barrier();

    // ---- phase 1 (kk = 1) ----
#pragma unroll
    for (int m = 0; m < 4; ++m)
      a[m] = *(const short8*)(cur + (wm * 64 + m * 16 + l15) * 128 + ((64 + lg * 16) ^ swz));
#pragma unroll
    for (int n = 0; n < 4; ++n)
      b[n] = *(const short8*)(cur + 16384 + (wn * 64 + n * 16 + l15) * 128 + ((64 + lg * 16) ^ swz));
    if (stage) {
      STAGE_B(stg, sk0, 1); STAGE_B(stg, sk0, 2); STAGE_B(stg, sk0, 3);
    }
    __builtin_amdgcn_s_barrier();
    asm volatile("s_waitcnt lgkmcnt(0)" ::: "memory");
    __builtin_amdgcn_sched_barrier(0);
    __builtin_amdgcn_s_setprio(1);
#pragma unroll
    for (int m = 0; m < 4; ++m)
#pragma unroll
      for (int n = 0; n < 4; ++n)
        acc[m][n] = MFMA16(a[m], b[n], acc[m][n]);
    __builtin_amdgcn_s_setprio(0);
    // counted wait: tile kt+1's 6 loads done; tile kt+2's 6 stay in flight
    if (stage) { asm volatile("s_waitcnt vmcnt(6)" ::: "memory"); }
    else       { asm volatile("s_waitcnt vmcnt(0)" ::: "memory"); }
    __builtin_amdgcn_s_barrier();

    char* old = cur; cur = nxt; nxt = stg; stg = old;
  }
#undef STAGE_A
#undef STAGE_B
#undef STAGE_ALL

  // ---- epilogue ----
  if (MODE == 1) {
#pragma unroll
    for (int m = 0; m < 4; ++m)
#pragma unroll
      for (int n = 0; n < 4; ++n) {
        int c = col0 + wn * 64 + n * 16 + l15;
        float bv = bias[c];
        int r0 = row0 + wm * 64 + m * 16 + lg * 4;
#pragma unroll
        for (int j = 0; j < 4; ++j)
          outp[(size_t)(r0 + j) * N + c] = acc[m][n][j] + bv;
      }
  } else {
#pragma unroll
    for (int m = 0; m < 4; ++m)
#pragma unroll
      for (int n = 0; n < 4; ++n) {
        int c = col0 + wn * 64 + n * 16 + l15;
        float bv = bias[c];
        int blk = c >> 7;                 // 128-col block: head h gets blocks 3h..3h+2
        int h = blk / 3, which = blk - h * 3;
        int d = c & 127;
        int r0 = row0 + wm * 64 + m * 16 + lg * 4;
        int b = r0 >> 11;
        int s0 = r0 & 2047;
        if (which < 2) {
          ushort_t* dst = (which == 0) ? out_q : out_k;
          size_t base = ((size_t)(b * NHEAD + h) * SEQ) * DK;
#pragma unroll
          for (int j = 0; j < 4; ++j)
            dst[base + (size_t)(s0 + j) * DK + d] = f2bf(acc[m][n][j] + bv);
        } else {
          size_t base = ((size_t)(b * NHEAD + h) * DK + d) * SEQ + s0;
          short4v tmp;
#pragma unroll
          for (int j = 0; j < 4; ++j) tmp[j] = (short)f2bf(acc[m][n][j] + bv);
          *(short4v*)&out_v[base] = tmp;
        }
      }
  }
}

// ---------------- flash attention: LDS-staged K/V, double-buffered, swizzled ----------------
__global__ __launch_bounds__(256, 2) void attn_k(const ushort_t* __restrict__ qws,
                                                 const ushort_t* __restrict__ kws,
                                                 const ushort_t* __restrict__ vtws,
                                                 ushort_t* __restrict__ ctx) {
  __shared__ __align__(16) ushort_t Ks[2][64 * 128];
  __shared__ __align__(16) ushort_t Vs[2][128 * 64];
  __shared__ __align__(16) ushort_t P[4][32 * 64];

  const int bid = blockIdx.y * gridDim.x + blockIdx.x;
  const int xcd = bid & 7, slot = bid >> 3;
  const int bh = xcd * 4 + (slot & 3);
  const int qt = slot >> 2;
  const int b = bh >> 4, h = bh & 15;
  const int t = threadIdx.x, wave = t >> 6, lane = t & 63;
  const int l15 = lane & 15, lg = lane >> 4;

  const ushort_t* Q  = qws  + (size_t)bh * SEQ * DK;
  const ushort_t* Kp = kws  + (size_t)bh * SEQ * DK;
  const ushort_t* VT = vtws + (size_t)bh * DK * SEQ;

  const int qr = qt * 128 + wave * 32;

  short8 qf[2][4];
#pragma unroll
  for (int m = 0; m < 2; ++m)
#pragma unroll
    for (int kk = 0; kk < 4; ++kk)
      qf[m][kk] = *(const short8*)&Q[(size_t)(qr + m * 16 + l15) * DK + kk * 32 + lg * 8];

  floatx4 o[2][8];
#pragma unroll
  for (int m = 0; m < 2; ++m)
#pragma unroll
    for (int n = 0; n < 8; ++n) o[m][n] = (floatx4){0.f, 0.f, 0.f, 0.f};
  float mrow[2] = {-1e30f, -1e30f};
  float lrowp[2] = {0.f, 0.f};

  char* Pb = (char*)&P[wave][0];
  const int swz = (l15 & 7) << 4;
  const float scale = 0.08838834764831845f;

  auto STAGE = [&](int buf, int kv0) {
#pragma unroll
    for (int t2 = 0; t2 < 4; ++t2) {
      int rowK = wave * 16 + t2 * 4 + (lane >> 4);
      int csK = ((lane & 15) * 16) ^ ((rowK & 7) << 4);
      GLOAD_LDS16((const char*)&Kp[(size_t)(kv0 + rowK) * DK] + csK,
                  (char*)&Ks[buf][0] + wave * 4096 + t2 * 1024);
      int rowV = wave * 32 + t2 * 8 + (lane >> 3);
      int csV = ((lane & 7) * 16) ^ ((rowV & 7) << 4);
      GLOAD_LDS16((const char*)&VT[(size_t)rowV * SEQ + kv0] + csV,
                  (char*)&Vs[buf][0] + wave * 4096 + t2 * 1024);
    }
  };

  STAGE(0, 0);
  __syncthreads();

  for (int it = 0; it < SEQ / 64; ++it) {
    const char* KsC = (const char*)&Ks[it & 1][0];
    const char* VsC = (const char*)&Vs[it & 1][0];
    if (it < SEQ / 64 - 1) STAGE((it + 1) & 1, (it + 1) * 64);

    floatx4 s[2][4];
#pragma unroll
    for (int m = 0; m < 2; ++m)
#pragma unroll
      for (int c = 0; c < 4; ++c) s[m][c] = (floatx4){0.f, 0.f, 0.f, 0.f};
#pragma unroll
    for (int c = 0; c < 4; ++c) {
      short8 kf[4];
#pragma unroll
      for (int kk = 0; kk < 4; ++kk)
        kf[kk] = *(const short8*)(KsC + (c * 16 + l15) * 256 + ((kk * 64 + lg * 16) ^ swz));
#pragma unroll
      for (int m = 0; m < 2; ++m)
#pragma unroll
        for (int kk = 0; kk < 4; ++kk)
          s[m][c] = MFMA16(kf[kk], qf[m][kk], s[m][c]);
    }

#pragma unroll
    for (int m = 0; m < 2; ++m) {
      float tt[4][4];
      float rm = -1e30f;
#pragma unroll
      for (int c = 0; c < 4; ++c)
#pragma unroll
        for (int j = 0; j < 4; ++j) {
          tt[c][j] = s[m][c][j] * scale;
          rm = fmaxf(rm, tt[c][j]);
        }
      rm = fmaxf(rm, __shfl_xor(rm, 16));
      rm = fmaxf(rm, __shfl_xor(rm, 32));

      if (__any(rm > mrow[m] + 8.f)) {
        float rmn = fmaxf(rm, mrow[m]);
        float corr = __expf(mrow[m] - rmn);
        mrow[m] = rmn;
        lrowp[m] *= corr;
        float co[4];
#pragma unroll
        for (int j = 0; j < 4; ++j) co[j] = __shfl(corr, lg * 4 + j);
#pragma unroll
        for (int n = 0; n < 8; ++n)
#pragma unroll
          for (int j = 0; j < 4; ++j) o[m][n][j] *= co[j];
      }

      float psum = 0.f;
#pragma unroll
      for (int c = 0; c < 4; ++c) {
        float p0 = __expf(tt[c][0] - mrow[m]);
        float p1 = __expf(tt[c][1] - mrow[m]);
        float p2 = __expf(tt[c][2] - mrow[m]);
        float p3 = __expf(tt[c][3] - mrow[m]);
        psum += (p0 + p1) + (p2 + p3);
        short4v pk;
        pk[0] = (short)f2bf(p0); pk[1] = (short)f2bf(p1);
        pk[2] = (short)f2bf(p2); pk[3] = (short)f2bf(p3);
        *(short4v*)(Pb + (m * 16 + l15) * 128 + ((c * 32 + lg * 8) ^ swz)) = pk;
      }
      lrowp[m] += psum;
    }

    asm volatile("s_waitcnt lgkmcnt(0)" ::: "memory");
    __builtin_amdgcn_sched_barrier(0);

    short8 pa[2][2];
#pragma unroll
    for (int m = 0; m < 2; ++m)
#pragma unroll
      for (int ch = 0; ch < 2; ++ch)
        pa[m][ch] = *(const short8*)(Pb + (m * 16 + l15) * 128 + ((ch * 64 + lg * 16) ^ swz));
#pragma unroll
    for (int n = 0; n < 8; ++n) {
      short8 v0 = *(const short8*)(VsC + (n * 16 + l15) * 128 + ((lg * 16) ^ swz));
      short8 v1 = *(const short8*)(VsC + (n * 16 + l15) * 128 + ((64 + lg * 16) ^ swz));
#pragma unroll
      for (int m = 0; m < 2; ++m) {
        o[m][n] = MFMA16(pa[m][0], v0, o[m][n]);
        o[m][n] = MFMA16(pa[m][1], v1, o[m][n]);
      }
    }
    __syncthreads();
  }

#pragma unroll
  for (int m = 0; m < 2; ++m) {
    lrowp[m] += __shfl_xor(lrowp[m], 16);
    lrowp[m] += __shfl_xor(lrowp[m], 32);
  }
#pragma unroll
  for (int m = 0; m < 2; ++m) {
    float rcp[4];
#pragma unroll
    for (int j = 0; j < 4; ++j) rcp[j] = 1.f / __shfl(lrowp[m], lg * 4 + j);
#pragma unroll
    for (int n = 0; n < 8; ++n)
#pragma unroll
      for (int j = 0; j < 4; ++j) {
        int row = qr + m * 16 + lg * 4 + j;
        ctx[(size_t)(b * SEQ + row) * D_MODEL + h * DK + n * 16 + l15] =
            f2bf(o[m][n][j] * rcp[j]);
      }
  }
}

// ---------------- launch ----------------
extern "C" void kernel_launch(void* const* d_in, const int* in_sizes, int n_in,
                              void* d_out, int out_size, void* d_ws, size_t ws_size,
                              hipStream_t stream) {
  const float* x    = (const float*)d_in[0];
  const float* Wqkv = (const float*)d_in[1];
  const float* bqkv = (const float*)d_in[2];
  const float* Wout = (const float*)d_in[3];
  const float* bout = (const float*)d_in[4];
  float* out = (float*)d_out;

  ushort_t* WqkvT = (ushort_t*)d_ws;
  ushort_t* WoutT = WqkvT + (size_t)6144 * 2048;
  ushort_t* qws   = WoutT + (size_t)2048 * 2048;
  ushort_t* kws   = qws + (size_t)8388608;
  ushort_t* vtws  = kws + (size_t)8388608;
  ushort_t* ctx   = vtws + (size_t)8388608;
  ushort_t* xb    = ctx + (size_t)8388608;

  cvt_k<<<4096, 256, 0, stream>>>(x, xb);
  transpose_cvt_k<<<dim3(6144 / 64, 2048 / 64), 256, 0, stream>>>(Wqkv, WqkvT, 2048, 6144);
  transpose_cvt_k<<<dim3(2048 / 64, 2048 / 64), 256, 0, stream>>>(Wout, WoutT, 2048, 2048);

  gemm8p<0><<<768, 512, 0, stream>>>(xb, WqkvT, bqkv, qws, kws, vtws, nullptr, 6144, 24);
  attn_k<<<dim3(16, 32), 256, 0, stream>>>(qws, kws, vtws, ctx);
  gemm8p<1><<<256, 512, 0, stream>>>(ctx, WoutT, bout, nullptr, nullptr, nullptr, out, 2048, 8);
}

// Round 11
// 379.629 us; speedup vs baseline: 2.7280x; 1.0449x over previous
//
#include <hip/hip_runtime.h>
#include <hip/hip_bf16.h>

typedef unsigned short ushort_t;
typedef short short8 __attribute__((ext_vector_type(8)));
typedef short short4v __attribute__((ext_vector_type(4)));
typedef float floatx4 __attribute__((ext_vector_type(4)));

#define MFMA16(a,b,c) __builtin_amdgcn_mfma_f32_16x16x32_bf16((a),(b),(c),0,0,0)

#define D_MODEL 2048
#define NHEAD   16
#define DK      128
#define SEQ     2048
#define BATCH   2

static __device__ __forceinline__ ushort_t f2bf(float f){
  union { float f; unsigned int i; } v; v.f = f;
  unsigned int r = v.i + 0x7FFFu + ((v.i >> 16) & 1u);
  return (ushort_t)(r >> 16);
}

typedef __attribute__((address_space(3))) void       lds_void_t;
typedef __attribute__((address_space(1))) const void gbl_void_t;
#define GLOAD_LDS16(g, l) \
  __builtin_amdgcn_global_load_lds((gbl_void_t*)(g), (lds_void_t*)(l), 16, 0, 0)

// ---------------- f32 -> bf16 convert (x -> xb) ----------------
__global__ __launch_bounds__(256) void cvt_k(const float* __restrict__ in,
                                             ushort_t* __restrict__ out) {
  int i = (blockIdx.x * 256 + threadIdx.x) * 8;
  floatx4 a = *(const floatx4*)&in[i];
  floatx4 b = *(const floatx4*)&in[i + 4];
  short8 r;
  for (int j = 0; j < 4; ++j) r[j] = (short)f2bf(a[j]);
  for (int j = 0; j < 4; ++j) r[4 + j] = (short)f2bf(b[j]);
  *(short8*)&out[i] = r;
}

// ---------------- transpose+convert: in f32 [R,C] -> out bf16 [C,R] ----------------
__global__ __launch_bounds__(256) void transpose_cvt_k(const float* __restrict__ in,
                                                       ushort_t* __restrict__ out,
                                                       int R, int C) {
  __shared__ ushort_t tile[64][65];
  int tr = blockIdx.y * 64, tc = blockIdx.x * 64;
  int t = threadIdx.x;
  for (int p = 0; p < 16; ++p) {
    int idx = t + p * 256;
    int r = idx >> 6, c = idx & 63;
    tile[r][c] = f2bf(in[(size_t)(tr + r) * C + (tc + c)]);
  }
  __syncthreads();
  for (int p = 0; p < 16; ++p) {
    int idx = t + p * 256;
    int r = idx >> 6, c = idx & 63;
    out[(size_t)(tc + r) * R + (tr + c)] = tile[c][r];
  }
}

// -------- phased NT GEMM: BM=128, BN=256, BK=64, 8 waves (2x4), K=2048 --------
// 3-buffer LDS rotation, depth-2 prefetch, counted vmcnt(6), ONE barrier per
// K-tile (per-wave lgkmcnt(0) precedes it => no pending ds_read at barrier;
// stage into buf X only after the barrier all reads of X precede).
// 2-D XCD chunking (bm_chunk x bn_chunk per XCD), bm-major within chunk so
// concurrent blocks share B columns (L2-resident panels).
// MODE 0: QKV projection -> scatter q/k/vT.  MODE 1: out-proj -> f32.
template <int MODE>
__global__ __launch_bounds__(512, 1) void gemm8p(const ushort_t* __restrict__ A,
                                                 const ushort_t* __restrict__ BT,
                                                 const float* __restrict__ bias,
                                                 ushort_t* __restrict__ out_q,
                                                 ushort_t* __restrict__ out_k,
                                                 ushort_t* __restrict__ out_v,
                                                 float* __restrict__ outp,
                                                 int N, int nbn,
                                                 int bm_chunk, int bn_chunk) {
  // per buffer: A 128x64 (16 KB) + B 256x64 (32 KB) = 48 KB; 3 buffers = 144 KB
  __shared__ __align__(16) ushort_t lds[3 * 24576];

  const int orig = blockIdx.x;
  const int xcd = orig & 7;
  const int local = orig >> 3;
  const int chunks_c = nbn / bn_chunk;
  const int bm = (xcd / chunks_c) * bm_chunk + (local % bm_chunk);
  const int bn = (xcd % chunks_c) * bn_chunk + (local / bm_chunk);
  const int row0 = bm * 128, col0 = bn * 256;

  const int t = threadIdx.x, wave = t >> 6, lane = t & 63;
  const int wm = wave >> 2, wn = wave & 3;
  const int l15 = lane & 15, lg = lane >> 4;
  const int swz = (l15 & 7) << 4;
  const int csrc = ((lane & 7) * 16) ^ ((lane >> 3) << 4);  // inverse-swizzled source bytes
  const int rsub = lane >> 3;                               // row within 8-row stage block

  char* buf0 = (char*)&lds[0];
  char* buf1 = buf0 + 49152;
  char* buf2 = buf1 + 49152;

  floatx4 acc[4][4];
#pragma unroll
  for (int m = 0; m < 4; ++m)
#pragma unroll
    for (int n = 0; n < 4; ++n) acc[m][n] = (floatx4){0.f, 0.f, 0.f, 0.f};

  // A occupies bytes [0, 16384), B occupies [16384, 49152) of each buffer.
#define STAGE_A(dst, k0, j) \
  GLOAD_LDS16((const char*)&A[(size_t)(row0 + (j) * 64 + wave * 8 + rsub) * 2048 + (k0)] + csrc, \
              (dst) + ((j) * 64 + wave * 8) * 128)
#define STAGE_B(dst, k0, j) \
  GLOAD_LDS16((const char*)&BT[(size_t)(col0 + (j) * 64 + wave * 8 + rsub) * 2048 + (k0)] + csrc, \
              (dst) + 16384 + ((j) * 64 + wave * 8) * 128)
#define STAGE_ALL(dst, k0) \
  do { STAGE_A(dst, k0, 0); STAGE_A(dst, k0, 1); \
       STAGE_B(dst, k0, 0); STAGE_B(dst, k0, 1); STAGE_B(dst, k0, 2); STAGE_B(dst, k0, 3); } while (0)

  // prologue: stage tiles 0 and 1; wait until tile 0 landed (<=6 outstanding)
  STAGE_ALL(buf0, 0);
  STAGE_ALL(buf1, 64);
  asm volatile("s_waitcnt vmcnt(6)" ::: "memory");
  __builtin_amdgcn_s_barrier();

  char* cur = buf0;
  char* nxt = buf1;
  char* stg = buf2;

  for (int kt = 0; kt < 32; ++kt) {
    const int sk0 = (kt + 2) * 64;
    const bool stage = (kt < 30);
    short8 a[4], b[4];

    // ---- phase 0 (kk = 0) ----
#pragma unroll
    for (int m = 0; m < 4; ++m)
      a[m] = *(const short8*)(cur + (wm * 64 + m * 16 + l15) * 128 + ((lg * 16) ^ swz));
#pragma unroll
    for (int n = 0; n < 4; ++n)
      b[n] = *(const short8*)(cur + 16384 + (wn * 64 + n * 16 + l15) * 128 + ((lg * 16) ^ swz));
    if (stage) {
      STAGE_A(stg, sk0, 0); STAGE_A(stg, sk0, 1); STAGE_B(stg, sk0, 0);
    }
    asm volatile("s_waitcnt lgkmcnt(0)" ::: "memory");
    __builtin_amdgcn_sched_barrier(0);
    __builtin_amdgcn_s_setprio(1);
#pragma unroll
    for (int m = 0; m < 4; ++m)
#pragma unroll
      for (int n = 0; n < 4; ++n)
        acc[m][n] = MFMA16(a[m], b[n], acc[m][n]);
    __builtin_amdgcn_s_setprio(0);

    // ---- phase 1 (kk = 1) ----
#pragma unroll
    for (int m = 0; m < 4; ++m)
      a[m] = *(const short8*)(cur + (wm * 64 + m * 16 + l15) * 128 + ((64 + lg * 16) ^ swz));
#pragma unroll
    for (int n = 0; n < 4; ++n)
      b[n] = *(const short8*)(cur + 16384 + (wn * 64 + n * 16 + l15) * 128 + ((64 + lg * 16) ^ swz));
    if (stage) {
      STAGE_B(stg, sk0, 1); STAGE_B(stg, sk0, 2); STAGE_B(stg, sk0, 3);
    }
    asm volatile("s_waitcnt lgkmcnt(0)" ::: "memory");
    __builtin_amdgcn_sched_barrier(0);
    __builtin_amdgcn_s_setprio(1);
#pragma unroll
    for (int m = 0; m < 4; ++m)
#pragma unroll
      for (int n = 0; n < 4; ++n)
        acc[m][n] = MFMA16(a[m], b[n], acc[m][n]);
    __builtin_amdgcn_s_setprio(0);

    // ---- single tile-end sync: tile kt+1 landed; kt+2 stays in flight ----
    if (stage) { asm volatile("s_waitcnt vmcnt(6) lgkmcnt(0)" ::: "memory"); }
    else       { asm volatile("s_waitcnt vmcnt(0) lgkmcnt(0)" ::: "memory"); }
    __builtin_amdgcn_s_barrier();

    char* old = cur; cur = nxt; nxt = stg; stg = old;
  }
#undef STAGE_A
#undef STAGE_B
#undef STAGE_ALL

  // ---- epilogue ----
  if (MODE == 1) {
#pragma unroll
    for (int m = 0; m < 4; ++m)
#pragma unroll
      for (int n = 0; n < 4; ++n) {
        int c = col0 + wn * 64 + n * 16 + l15;
        float bv = bias[c];
        int r0 = row0 + wm * 64 + m * 16 + lg * 4;
#pragma unroll
        for (int j = 0; j < 4; ++j)
          outp[(size_t)(r0 + j) * N + c] = acc[m][n][j] + bv;
      }
  } else {
#pragma unroll
    for (int m = 0; m < 4; ++m)
#pragma unroll
      for (int n = 0; n < 4; ++n) {
        int c = col0 + wn * 64 + n * 16 + l15;
        float bv = bias[c];
        int blk = c >> 7;                 // 128-col block: head h gets blocks 3h..3h+2
        int h = blk / 3, which = blk - h * 3;
        int d = c & 127;
        int r0 = row0 + wm * 64 + m * 16 + lg * 4;
        int b = r0 >> 11;
        int s0 = r0 & 2047;
        if (which < 2) {
          ushort_t* dst = (which == 0) ? out_q : out_k;
          size_t base = ((size_t)(b * NHEAD + h) * SEQ) * DK;
#pragma unroll
          for (int j = 0; j < 4; ++j)
            dst[base + (size_t)(s0 + j) * DK + d] = f2bf(acc[m][n][j] + bv);
        } else {
          size_t base = ((size_t)(b * NHEAD + h) * DK + d) * SEQ + s0;
          short4v tmp;
#pragma unroll
          for (int j = 0; j < 4; ++j) tmp[j] = (short)f2bf(acc[m][n][j] + bv);
          *(short4v*)&out_v[base] = tmp;
        }
      }
  }
}

// ---------------- flash attention: LDS-staged K/V, double-buffered, swizzled ----------------
__global__ __launch_bounds__(256, 2) void attn_k(const ushort_t* __restrict__ qws,
                                                 const ushort_t* __restrict__ kws,
                                                 const ushort_t* __restrict__ vtws,
                                                 ushort_t* __restrict__ ctx) {
  __shared__ __align__(16) ushort_t Ks[2][64 * 128];
  __shared__ __align__(16) ushort_t Vs[2][128 * 64];
  __shared__ __align__(16) ushort_t P[4][32 * 64];

  const int bid = blockIdx.y * gridDim.x + blockIdx.x;
  const int xcd = bid & 7, slot = bid >> 3;
  const int bh = xcd * 4 + (slot & 3);
  const int qt = slot >> 2;
  const int b = bh >> 4, h = bh & 15;
  const int t = threadIdx.x, wave = t >> 6, lane = t & 63;
  const int l15 = lane & 15, lg = lane >> 4;

  const ushort_t* Q  = qws  + (size_t)bh * SEQ * DK;
  const ushort_t* Kp = kws  + (size_t)bh * SEQ * DK;
  const ushort_t* VT = vtws + (size_t)bh * DK * SEQ;

  const int qr = qt * 128 + wave * 32;

  short8 qf[2][4];
#pragma unroll
  for (int m = 0; m < 2; ++m)
#pragma unroll
    for (int kk = 0; kk < 4; ++kk)
      qf[m][kk] = *(const short8*)&Q[(size_t)(qr + m * 16 + l15) * DK + kk * 32 + lg * 8];

  floatx4 o[2][8];
#pragma unroll
  for (int m = 0; m < 2; ++m)
#pragma unroll
    for (int n = 0; n < 8; ++n) o[m][n] = (floatx4){0.f, 0.f, 0.f, 0.f};
  float mrow[2] = {-1e30f, -1e30f};
  float lrowp[2] = {0.f, 0.f};

  char* Pb = (char*)&P[wave][0];
  const int swz = (l15 & 7) << 4;
  const float scale = 0.08838834764831845f;

  auto STAGE = [&](int buf, int kv0) {
#pragma unroll
    for (int t2 = 0; t2 < 4; ++t2) {
      int rowK = wave * 16 + t2 * 4 + (lane >> 4);
      int csK = ((lane & 15) * 16) ^ ((rowK & 7) << 4);
      GLOAD_LDS16((const char*)&Kp[(size_t)(kv0 + rowK) * DK] + csK,
                  (char*)&Ks[buf][0] + wave * 4096 + t2 * 1024);
      int rowV = wave * 32 + t2 * 8 + (lane >> 3);
      int csV = ((lane & 7) * 16) ^ ((rowV & 7) << 4);
      GLOAD_LDS16((const char*)&VT[(size_t)rowV * SEQ + kv0] + csV,
                  (char*)&Vs[buf][0] + wave * 4096 + t2 * 1024);
    }
  };

  STAGE(0, 0);
  __syncthreads();

  for (int it = 0; it < SEQ / 64; ++it) {
    const char* KsC = (const char*)&Ks[it & 1][0];
    const char* VsC = (const char*)&Vs[it & 1][0];
    if (it < SEQ / 64 - 1) STAGE((it + 1) & 1, (it + 1) * 64);

    floatx4 s[2][4];
#pragma unroll
    for (int m = 0; m < 2; ++m)
#pragma unroll
      for (int c = 0; c < 4; ++c) s[m][c] = (floatx4){0.f, 0.f, 0.f, 0.f};
#pragma unroll
    for (int c = 0; c < 4; ++c) {
      short8 kf[4];
#pragma unroll
      for (int kk = 0; kk < 4; ++kk)
        kf[kk] = *(const short8*)(KsC + (c * 16 + l15) * 256 + ((kk * 64 + lg * 16) ^ swz));
#pragma unroll
      for (int m = 0; m < 2; ++m)
#pragma unroll
        for (int kk = 0; kk < 4; ++kk)
          s[m][c] = MFMA16(kf[kk], qf[m][kk], s[m][c]);
    }

#pragma unroll
    for (int m = 0; m < 2; ++m) {
      float tt[4][4];
      float rm = -1e30f;
#pragma unroll
      for (int c = 0; c < 4; ++c)
#pragma unroll
        for (int j = 0; j < 4; ++j) {
          tt[c][j] = s[m][c][j] * scale;
          rm = fmaxf(rm, tt[c][j]);
        }
      rm = fmaxf(rm, __shfl_xor(rm, 16));
      rm = fmaxf(rm, __shfl_xor(rm, 32));

      if (__any(rm > mrow[m] + 8.f)) {
        float rmn = fmaxf(rm, mrow[m]);
        float corr = __expf(mrow[m] - rmn);
        mrow[m] = rmn;
        lrowp[m] *= corr;
        float co[4];
#pragma unroll
        for (int j = 0; j < 4; ++j) co[j] = __shfl(corr, lg * 4 + j);
#pragma unroll
        for (int n = 0; n < 8; ++n)
#pragma unroll
          for (int j = 0; j < 4; ++j) o[m][n][j] *= co[j];
      }

      float psum = 0.f;
#pragma unroll
      for (int c = 0; c < 4; ++c) {
        float p0 = __expf(tt[c][0] - mrow[m]);
        float p1 = __expf(tt[c][1] - mrow[m]);
        float p2 = __expf(tt[c][2] - mrow[m]);
        float p3 = __expf(tt[c][3] - mrow[m]);
        psum += (p0 + p1) + (p2 + p3);
        short4v pk;
        pk[0] = (short)f2bf(p0); pk[1] = (short)f2bf(p1);
        pk[2] = (short)f2bf(p2); pk[3] = (short)f2bf(p3);
        *(short4v*)(Pb + (m * 16 + l15) * 128 + ((c * 32 + lg * 8) ^ swz)) = pk;
      }
      lrowp[m] += psum;
    }

    asm volatile("s_waitcnt lgkmcnt(0)" ::: "memory");
    __builtin_amdgcn_sched_barrier(0);

    short8 pa[2][2];
#pragma unroll
    for (int m = 0; m < 2; ++m)
#pragma unroll
      for (int ch = 0; ch < 2; ++ch)
        pa[m][ch] = *(const short8*)(Pb + (m * 16 + l15) * 128 + ((ch * 64 + lg * 16) ^ swz));
#pragma unroll
    for (int n = 0; n < 8; ++n) {
      short8 v0 = *(const short8*)(VsC + (n * 16 + l15) * 128 + ((lg * 16) ^ swz));
      short8 v1 = *(const short8*)(VsC + (n * 16 + l15) * 128 + ((64 + lg * 16) ^ swz));
#pragma unroll
      for (int m = 0; m < 2; ++m) {
        o[m][n] = MFMA16(pa[m][0], v0, o[m][n]);
        o[m][n] = MFMA16(pa[m][1], v1, o[m][n]);
      }
    }
    __syncthreads();
  }

#pragma unroll
  for (int m = 0; m < 2; ++m) {
    lrowp[m] += __shfl_xor(lrowp[m], 16);
    lrowp[m] += __shfl_xor(lrowp[m], 32);
  }
#pragma unroll
  for (int m = 0; m < 2; ++m) {
    float rcp[4];
#pragma unroll
    for (int j = 0; j < 4; ++j) rcp[j] = 1.f / __shfl(lrowp[m], lg * 4 + j);
#pragma unroll
    for (int n = 0; n < 8; ++n)
#pragma unroll
      for (int j = 0; j < 4; ++j) {
        int row = qr + m * 16 + lg * 4 + j;
        ctx[(size_t)(b * SEQ + row) * D_MODEL + h * DK + n * 16 + l15] =
            f2bf(o[m][n][j] * rcp[j]);
      }
  }
}

// ---------------- launch ----------------
extern "C" void kernel_launch(void* const* d_in, const int* in_sizes, int n_in,
                              void* d_out, int out_size, void* d_ws, size_t ws_size,
                              hipStream_t stream) {
  const float* x    = (const float*)d_in[0];
  const float* Wqkv = (const float*)d_in[1];
  const float* bqkv = (const float*)d_in[2];
  const float* Wout = (const float*)d_in[3];
  const float* bout = (const float*)d_in[4];
  float* out = (float*)d_out;

  ushort_t* WqkvT = (ushort_t*)d_ws;
  ushort_t* WoutT = WqkvT + (size_t)6144 * 2048;
  ushort_t* qws   = WoutT + (size_t)2048 * 2048;
  ushort_t* kws   = qws + (size_t)8388608;
  ushort_t* vtws  = kws + (size_t)8388608;
  ushort_t* ctx   = vtws + (size_t)8388608;
  ushort_t* xb    = ctx + (size_t)8388608;

  cvt_k<<<4096, 256, 0, stream>>>(x, xb);
  transpose_cvt_k<<<dim3(6144 / 64, 2048 / 64), 256, 0, stream>>>(Wqkv, WqkvT, 2048, 6144);
  transpose_cvt_k<<<dim3(2048 / 64, 2048 / 64), 256, 0, stream>>>(Wout, WoutT, 2048, 2048);

  // QKV: grid 32bm x 24bn = 768, per-XCD chunk 8bm x 12bn, bm-major within chunk
  gemm8p<0><<<768, 512, 0, stream>>>(xb, WqkvT, bqkv, qws, kws, vtws, nullptr, 6144, 24, 8, 12);
  attn_k<<<dim3(16, 32), 256, 0, stream>>>(qws, kws, vtws, ctx);
  // out-proj: grid 32bm x 8bn = 256, per-XCD chunk 8bm x 4bn
  gemm8p<1><<<256, 512, 0, stream>>>(ctx, WoutT, bout, nullptr, nullptr, nullptr, out, 2048, 8, 8, 4);
}